// Round 3
// 488.821 us; speedup vs baseline: 1.0632x; 1.0632x over previous
//
#include <hip/hip_runtime.h>

typedef unsigned short ushort_t;
typedef unsigned int uint_t;
typedef __attribute__((ext_vector_type(8))) short short8;
typedef __attribute__((ext_vector_type(4))) float f32x4;

#define Bv 16
#define Lv 1025
#define LpD 1088          // 17*64 padded sequence
#define Cv 1024
#define Hv 16
#define BHv 256
#define Mv 16400          // valid rows
#define Mp 16512          // 129*128 padded rows

#define MFMA(a, b, c) __builtin_amdgcn_mfma_f32_16x16x32_bf16(a, b, c, 0, 0, 0)

__device__ __forceinline__ ushort_t f2b(float x) {
    uint_t u = __float_as_uint(x);
    u = (u + 0x7FFFu + ((u >> 16) & 1u)) >> 16;   // RNE
    return (ushort_t)u;
}
__device__ __forceinline__ float b2f(ushort_t v) {
    return __uint_as_float(((uint_t)v) << 16);
}
// packed f32x2 -> bf16x2 (1 VALU op on gfx950; RNE)
__device__ __forceinline__ uint_t pk2(float a, float b) {
#if __has_builtin(__builtin_amdgcn_cvt_pk_bf16_f32)
    typedef __attribute__((ext_vector_type(2))) __bf16 bf16x2;
    bf16x2 r = __builtin_amdgcn_cvt_pk_bf16_f32(a, b);
    return *(uint_t*)&r;
#else
    return (uint_t)f2b(a) | ((uint_t)f2b(b) << 16);
#endif
}

// async global->LDS DMA, 16 B per lane; LDS dest = wave-uniform base + 16*lane
__device__ __forceinline__ void gl2lds16(const ushort_t* g, void* lds) {
    __builtin_amdgcn_global_load_lds(
        (const __attribute__((address_space(1))) void*)g,
        (__attribute__((address_space(3))) void*)lds, 16, 0, 0);
}

// XOR-swizzled frag read from an unpadded [rows][64] bf16 LDS tile:
// physical 16-B chunk p holds logical chunk p ^ (row & 7).
__device__ __forceinline__ short8 frag(const ushort_t* base, int row, int chunk) {
    return *(const short8*)(base + row * 64 + ((chunk ^ (row & 7)) << 3));
}

// ---------------- fp32 -> bf16 convert (pads tail with zeros) ---------------
__global__ __launch_bounds__(256) void conv_bf16(const float* __restrict__ s,
                                                 ushort_t* __restrict__ d,
                                                 int n_valid, int n_total) {
    int i = (blockIdx.x * 256 + threadIdx.x) * 4;
    if (i >= n_total) return;
    float4 v = make_float4(0.f, 0.f, 0.f, 0.f);
    if (i < n_valid) v = *(const float4*)(s + i);   // n_valid multiple of 4
    ushort4 o;
    o.x = f2b(v.x); o.y = f2b(v.y); o.z = f2b(v.z); o.w = f2b(v.w);
    *(ushort4*)(d + i) = o;
}

// ---------------- QKV GEMM: C[m][n] = sum_k A[m][k] W[n][k] -----------------
// RoPE fused into the epilogue (reads the full 64-dim head row from St; the
// rotate-half partner of dim d is d^32 in the same row).
__global__ __launch_bounds__(256, 4) void gemm_qkv(const ushort_t* __restrict__ A,
                                                   const ushort_t* __restrict__ W,
                                                   ushort_t* __restrict__ Q,
                                                   ushort_t* __restrict__ K,
                                                   ushort_t* __restrict__ V,
                                                   const float* __restrict__ sinp,
                                                   const float* __restrict__ cosp) {
    __shared__ uint4 sm[2112];                     // 33792 B
    ushort_t* As = (ushort_t*)sm;                  // [128][64] swizzled
    ushort_t* Bs = As + 128 * 64;                  // [128][64] swizzled
    const int t = threadIdx.x;
    const int w = t >> 6, l = t & 63;
    const int m0 = blockIdx.y * 128, n0 = blockIdx.x * 128;
    const int wm = (w >> 1) * 64, wn = (w & 1) * 64;
    const int srow = (w * 32) + (l >> 3);          // staging row base for i=0
    const int scs = (l & 7) ^ (srow & 7);          // swizzled chunk
    f32x4 acc[4][4] = {};
    for (int k0 = 0; k0 < 1024; k0 += 64) {
        __syncthreads();                           // prev frag reads done
#pragma unroll
        for (int i = 0; i < 4; i++) {
            int row = srow + i * 8;
            gl2lds16(A + (size_t)(m0 + row) * 1024 + k0 + scs * 8,
                     As + (w * 32 + i * 8) * 64);
            gl2lds16(W + (size_t)(n0 + row) * 1024 + k0 + scs * 8,
                     Bs + (w * 32 + i * 8) * 64);
        }
        __syncthreads();                           // drains vmcnt(0): LDS valid
#pragma unroll
        for (int kb = 0; kb < 2; kb++) {
            short8 af[4], bf[4];
#pragma unroll
            for (int mb = 0; mb < 4; mb++)
                af[mb] = frag(As, wm + mb * 16 + (l & 15), kb * 4 + (l >> 4));
#pragma unroll
            for (int nb = 0; nb < 4; nb++)
                bf[nb] = frag(Bs, wn + nb * 16 + (l & 15), kb * 4 + (l >> 4));
#pragma unroll
            for (int mb = 0; mb < 4; mb++)
#pragma unroll
                for (int nb = 0; nb < 4; nb++)
                    acc[mb][nb] = MFMA(af[mb], bf[nb], acc[mb][nb]);
        }
    }
    // ---- epilogue: LDS-staged, coalesced 128-B stores, fused RoPE ----
    __syncthreads();
    ushort_t (*St)[132] = (ushort_t(*)[132])sm;    // 128x132 bf16 = 33792 B
#pragma unroll
    for (int mb = 0; mb < 4; mb++)
#pragma unroll
        for (int r = 0; r < 4; r++)
#pragma unroll
            for (int nb = 0; nb < 4; nb++)
                St[wm + mb * 16 + (l >> 4) * 4 + r][wn + nb * 16 + (l & 15)] =
                    f2b(acc[mb][nb][r]);
    __syncthreads();
#pragma unroll
    for (int it = 0; it < 8; it++) {
        int seg = it * 32 + w * 8 + (l >> 3);
        int mr = seg >> 1, p = seg & 1;
        int m = m0 + mr;
        if (m >= Mv) continue;
        int b = m / 1025, lseq = m - b * 1025;
        int n = n0 + p * 64;
        int which = n >> 10, h = (n >> 6) & 15;
        ushort_t* dst = (which == 0) ? Q : ((which == 1) ? K : V);
        const int d0 = (l & 7) * 8;
        size_t doff = ((size_t)(b * Hv + h) * LpD + lseq) * 64 + d0;
        if (which <= 1 && lseq > 0) {
            // RoPE on patch rows of Q and K
            const ushort_t* rowp = &St[mr][p * 64];
            const float* cw = cosp + (lseq - 1) * 64 + d0;
            const float* sw = sinp + (lseq - 1) * 64 + d0;
            float4 c0 = *(const float4*)cw, c1 = *(const float4*)(cw + 4);
            float4 s0 = *(const float4*)sw, s1 = *(const float4*)(sw + 4);
            float cc[8] = {c0.x, c0.y, c0.z, c0.w, c1.x, c1.y, c1.z, c1.w};
            float ss[8] = {s0.x, s0.y, s0.z, s0.w, s1.x, s1.y, s1.z, s1.w};
            float sgn = (d0 < 32) ? -1.f : 1.f;    // rot = [-t2, t1]
            uint_t ov[4];
#pragma unroll
            for (int jj = 0; jj < 4; jj++) {
                float f0 = b2f(rowp[d0 + jj * 2]);
                float f1 = b2f(rowp[d0 + jj * 2 + 1]);
                float r0 = b2f(rowp[(d0 ^ 32) + jj * 2]) * sgn;
                float r1 = b2f(rowp[(d0 ^ 32) + jj * 2 + 1]) * sgn;
                ov[jj] = pk2(f0 * cc[jj * 2] + r0 * ss[jj * 2],
                             f1 * cc[jj * 2 + 1] + r1 * ss[jj * 2 + 1]);
            }
            *(uint4*)(dst + doff) = *(uint4*)ov;
        } else {
            *(uint4*)(dst + doff) = *(const uint4*)&St[mr][p * 64 + d0];
        }
    }
}

// ---------------- V transpose: [BH][Lp][64] -> [BH][64][Lp] -----------------
__global__ __launch_bounds__(256) void transpose_v(const ushort_t* __restrict__ Vb,
                                                   ushort_t* __restrict__ Vt) {
    __shared__ ushort_t Ts[64][72];
    const int t = threadIdx.x;
    const int l0 = blockIdx.x * 64, bh = blockIdx.y;
#pragma unroll
    for (int i = 0; i < 2; i++) {
        int c = t + 256 * i; int row = c >> 3, cir = c & 7;
        *(uint4*)&Ts[row][cir * 8] =
            *(const uint4*)(Vb + ((size_t)bh * LpD + l0 + row) * 64 + cir * 8);
    }
    __syncthreads();
#pragma unroll
    for (int i = 0; i < 2; i++) {
        int c = t + 256 * i; int d = c >> 3, lg = c & 7;
        short8 v;
#pragma unroll
        for (int j = 0; j < 8; j++) v[j] = (short)Ts[lg * 8 + j][d];
        *(short8*)(Vt + ((size_t)bh * 64 + d) * LpD + l0 + lg * 8) = v;
    }
}

// ---------------- Attention: block = (q-tile 64, bh). Unnormalized exp. -----
// Double-buffered K/V DMA with counted vmcnt + raw barriers: tile kt+1's
// global_load_lds stay in flight while tile kt is computed (never drain
// vmcnt to 0 in the main loop). setprio(1) around the PV MFMA cluster.
__global__ __launch_bounds__(256, 3) void attn_mfma(const ushort_t* __restrict__ Qb,
                                                    const ushort_t* __restrict__ Kb,
                                                    const ushort_t* __restrict__ Vt,
                                                    ushort_t* __restrict__ AO) {
    __shared__ ushort_t Qs[64 * 64];               // swizzled
    __shared__ ushort_t Kd[2][64 * 64];            // double-buffered, swizzled
    __shared__ ushort_t Vd[2][64 * 64];
    __shared__ ushort_t Ps[64][72];
    const int t = threadIdx.x, w = t >> 6, l = t & 63;
    const int qt = blockIdx.x, bh = blockIdx.y;
    const int q0 = qt * 64;
    const size_t kbase = (size_t)bh * LpD * 64;
    const size_t vbase = (size_t)bh * 64 * LpD;
    const int scs = (l & 7) ^ ((l >> 3) & 7);      // swizzled chunk for staging

#pragma unroll
    for (int i = 0; i < 2; i++) {                  // Q tile: 16 rows per wave
        int row = w * 16 + i * 8 + (l >> 3);
        gl2lds16(Qb + kbase + (size_t)(q0 + row) * 64 + scs * 8,
                 Qs + (w * 16 + i * 8) * 64);
    }
#pragma unroll
    for (int i = 0; i < 2; i++) {                  // K/V tile 0 into buffer 0
        int row = w * 16 + i * 8 + (l >> 3);
        gl2lds16(Kb + kbase + (size_t)row * 64 + scs * 8,
                 Kd[0] + (w * 16 + i * 8) * 64);
        gl2lds16(Vt + vbase + (size_t)row * LpD + scs * 8,
                 Vd[0] + (w * 16 + i * 8) * 64);
    }
    asm volatile("s_waitcnt vmcnt(4)" ::: "memory");   // Q resident (tile0 may fly)
    asm volatile("s_barrier" ::: "memory");
    short8 aq0 = frag(Qs, w * 16 + (l & 15), l >> 4);
    short8 aq1 = frag(Qs, w * 16 + (l & 15), 4 + (l >> 4));

    short8 ones;
#pragma unroll
    for (int j = 0; j < 8; j++) ones[j] = (short)0x3F80;   // 1.0 bf16
    f32x4 o[4] = {};
    f32x4 sacc = {};
    const float CE = 0.18033688011112042f;  // log2(e)/8: exp(s/8) = exp2(s*CE)

    for (int kt = 0; kt < 17; kt++) {
        const ushort_t* Ks = Kd[kt & 1];
        const ushort_t* Vs = Vd[kt & 1];
        if (kt < 16) {                             // prefetch tile kt+1
#pragma unroll
            for (int i = 0; i < 2; i++) {
                int row = w * 16 + i * 8 + (l >> 3);
                gl2lds16(Kb + kbase + (size_t)((kt + 1) * 64 + row) * 64 + scs * 8,
                         Kd[(kt + 1) & 1] + (w * 16 + i * 8) * 64);
                gl2lds16(Vt + vbase + (size_t)row * LpD + (kt + 1) * 64 + scs * 8,
                         Vd[(kt + 1) & 1] + (w * 16 + i * 8) * 64);
            }
            asm volatile("s_waitcnt vmcnt(4)" ::: "memory");  // tile kt landed
        } else {
            asm volatile("s_waitcnt vmcnt(0)" ::: "memory");  // last tile
        }
        asm volatile("s_barrier" ::: "memory");    // all waves: tile kt valid
#pragma unroll
        for (int cb = 0; cb < 4; cb++) {
            short8 bk0 = frag(Ks, cb * 16 + (l & 15), l >> 4);
            short8 bk1 = frag(Ks, cb * 16 + (l & 15), 4 + (l >> 4));
            f32x4 s = {};
            s = MFMA(aq0, bk0, s);
            s = MFMA(aq1, bk1, s);
            float p4[4];
#pragma unroll
            for (int r = 0; r < 4; r++) p4[r] = exp2f(s[r] * CE);
            if (kt == 16) {                        // uniform branch: mask pad keys
                int key = 1024 + cb * 16 + (l & 15);
                if (key >= Lv) { p4[0] = p4[1] = p4[2] = p4[3] = 0.f; }
            }
            uint_t pk01 = pk2(p4[0], p4[1]);
            uint_t pk23 = pk2(p4[2], p4[3]);
            ushort_t* pr = &Ps[w * 16 + (l >> 4) * 4][cb * 16 + (l & 15)];
            pr[0 * 72] = (ushort_t)pk01;
            pr[1 * 72] = (ushort_t)(pk01 >> 16);
            pr[2 * 72] = (ushort_t)pk23;
            pr[3 * 72] = (ushort_t)(pk23 >> 16);
        }
        // own-wave rows only -> no barrier; compiler inserts lgkmcnt waits
        short8 ap0 = *(const short8*)&Ps[w * 16 + (l & 15)][(l >> 4) * 8];
        short8 ap1 = *(const short8*)&Ps[w * 16 + (l & 15)][32 + (l >> 4) * 8];
        __builtin_amdgcn_s_setprio(1);
        sacc = MFMA(ap0, ones, sacc);              // exact row-sums of rounded P
        sacc = MFMA(ap1, ones, sacc);
#pragma unroll
        for (int cb = 0; cb < 4; cb++) {
            short8 bv0 = frag(Vs, cb * 16 + (l & 15), l >> 4);
            short8 bv1 = frag(Vs, cb * 16 + (l & 15), 4 + (l >> 4));
            o[cb] = MFMA(ap0, bv0, o[cb]);
            o[cb] = MFMA(ap1, bv1, o[cb]);
        }
        __builtin_amdgcn_s_setprio(0);
        asm volatile("s_barrier" ::: "memory");    // reads of buf[kt&1] done
    }
    const int b = bh >> 4, h = bh & 15;
#pragma unroll
    for (int r = 0; r < 4; r++) {
        int lq = q0 + w * 16 + (l >> 4) * 4 + r;
        if (lq >= Lv) continue;
        float inv = 1.f / sacc[r];
        size_t ob = ((size_t)(b * 1025 + lq)) * 1024 + h * 64;
#pragma unroll
        for (int cb = 0; cb < 4; cb++)
            AO[ob + cb * 16 + (l & 15)] = f2b(o[cb][r] * inv);
    }
}

// ---------------- Proj GEMM + bias, fp32 out --------------------------------
__global__ __launch_bounds__(256, 4) void gemm_proj(const ushort_t* __restrict__ A,
                                                    const ushort_t* __restrict__ W,
                                                    const float* __restrict__ bias,
                                                    float* __restrict__ out) {
    __shared__ uint4 sm[2112];                     // 33792 B
    ushort_t* As = (ushort_t*)sm;
    ushort_t* Bs = As + 128 * 64;
    const int t = threadIdx.x;
    const int w = t >> 6, l = t & 63;
    const int m0 = blockIdx.y * 128, n0 = blockIdx.x * 128;
    const int wm = (w >> 1) * 64, wn = (w & 1) * 64;
    const int srow = (w * 32) + (l >> 3);
    const int scs = (l & 7) ^ (srow & 7);
    f32x4 acc[4][4] = {};
    for (int k0 = 0; k0 < 1024; k0 += 64) {
        __syncthreads();
#pragma unroll
        for (int i = 0; i < 4; i++) {
            int row = srow + i * 8;
            gl2lds16(A + (size_t)(m0 + row) * 1024 + k0 + scs * 8,
                     As + (w * 32 + i * 8) * 64);
            gl2lds16(W + (size_t)(n0 + row) * 1024 + k0 + scs * 8,
                     Bs + (w * 32 + i * 8) * 64);
        }
        __syncthreads();
#pragma unroll
        for (int kb = 0; kb < 2; kb++) {
            short8 af[4], bf[4];
#pragma unroll
            for (int mb = 0; mb < 4; mb++)
                af[mb] = frag(As, wm + mb * 16 + (l & 15), kb * 4 + (l >> 4));
#pragma unroll
            for (int nb = 0; nb < 4; nb++)
                bf[nb] = frag(Bs, wn + nb * 16 + (l & 15), kb * 4 + (l >> 4));
#pragma unroll
            for (int mb = 0; mb < 4; mb++)
#pragma unroll
                for (int nb = 0; nb < 4; nb++)
                    acc[mb][nb] = MFMA(af[mb], bf[nb], acc[mb][nb]);
        }
    }
    // ---- epilogue: stage fp32 in 64-row halves, store 512-B rows ----
    float bias4[4];
#pragma unroll
    for (int nb = 0; nb < 4; nb++) bias4[nb] = bias[n0 + wn + nb * 16 + (l & 15)];
    float (*Sf)[132] = (float(*)[132])sm;          // 64x132 fp32 = 33792 B
#pragma unroll
    for (int half = 0; half < 2; half++) {
        __syncthreads();
        if ((w >> 1) == half) {
#pragma unroll
            for (int mb = 0; mb < 4; mb++)
#pragma unroll
                for (int r = 0; r < 4; r++)
#pragma unroll
                    for (int nb = 0; nb < 4; nb++)
                        Sf[mb * 16 + (l >> 4) * 4 + r][wn + nb * 16 + (l & 15)] =
                            acc[mb][nb][r] + bias4[nb];
        }
        __syncthreads();
#pragma unroll
        for (int it = 0; it < 8; it++) {
            int rr = it * 8 + w * 2 + (l >> 5);
            int m = m0 + half * 64 + rr;
            if (m < Mv)
                *(float4*)(out + (size_t)m * 1024 + n0 + (l & 31) * 4) =
                    *(const float4*)&Sf[rr][(l & 31) * 4];
        }
    }
}

extern "C" void kernel_launch(void* const* d_in, const int* in_sizes, int n_in,
                              void* d_out, int out_size, void* d_ws, size_t ws_size,
                              hipStream_t stream) {
    (void)in_sizes; (void)n_in; (void)out_size; (void)ws_size;
    const float* x      = (const float*)d_in[0];
    const float* sinp   = (const float*)d_in[1];
    const float* cosp   = (const float*)d_in[2];
    const float* qkv_w  = (const float*)d_in[3];
    const float* proj_w = (const float*)d_in[4];
    const float* proj_b = (const float*)d_in[5];
    float* out = (float*)d_out;

    const size_t SZH = (size_t)BHv * LpD * 64;     // per Q/K/V tensor (bf16 elems)
    ushort_t* xb  = (ushort_t*)d_ws;               // [Mp][1024]
    ushort_t* qwb = xb + (size_t)Mp * 1024;        // [3072][1024]
    ushort_t* pwb = qwb + (size_t)3072 * 1024;     // [1024][1024]
    ushort_t* Qb  = pwb + (size_t)1024 * 1024;     // [BH][Lp][64]
    ushort_t* Kb  = Qb + SZH;
    ushort_t* Vb  = Kb + SZH;
    ushort_t* Vt  = Vb + SZH;                      // [BH][64][Lp]
    ushort_t* AO  = Vt + SZH;                      // [Mp][1024]

    dim3 blk(256);
    conv_bf16<<<dim3(Mp * 1024 / 1024), blk, 0, stream>>>(x, xb, Mv * 1024, Mp * 1024);
    conv_bf16<<<dim3(3072 * 1024 / 1024), blk, 0, stream>>>(qkv_w, qwb, 3072 * 1024, 3072 * 1024);
    conv_bf16<<<dim3(1024 * 1024 / 1024), blk, 0, stream>>>(proj_w, pwb, 1024 * 1024, 1024 * 1024);
    gemm_qkv<<<dim3(24, 129), blk, 0, stream>>>(xb, qwb, Qb, Kb, Vb, sinp, cosp);
    transpose_v<<<dim3(17, BHv), blk, 0, stream>>>(Vb, Vt);
    attn_mfma<<<dim3(17, BHv), blk, 0, stream>>>(Qb, Kb, Vt, AO);
    gemm_proj<<<dim3(8, 129), blk, 0, stream>>>(AO, pwb, proj_b, out);
}

// Round 4
// 487.344 us; speedup vs baseline: 1.0664x; 1.0030x over previous
//
#include <hip/hip_runtime.h>

typedef unsigned short ushort_t;
typedef unsigned int uint_t;
typedef __attribute__((ext_vector_type(8))) short short8;
typedef __attribute__((ext_vector_type(4))) float f32x4;

#define Bv 16
#define Lv 1025
#define LpD 1088          // 17*64 padded sequence
#define Cv 1024
#define Hv 16
#define BHv 256
#define Mv 16400          // valid rows
#define Mp 16512          // 129*128 padded rows

#define MFMA(a, b, c) __builtin_amdgcn_mfma_f32_16x16x32_bf16(a, b, c, 0, 0, 0)

__device__ __forceinline__ ushort_t f2b(float x) {
    uint_t u = __float_as_uint(x);
    u = (u + 0x7FFFu + ((u >> 16) & 1u)) >> 16;   // RNE
    return (ushort_t)u;
}
__device__ __forceinline__ float b2f(ushort_t v) {
    return __uint_as_float(((uint_t)v) << 16);
}
// packed f32x2 -> bf16x2 (1 VALU op on gfx950; RNE)
__device__ __forceinline__ uint_t pk2(float a, float b) {
#if __has_builtin(__builtin_amdgcn_cvt_pk_bf16_f32)
    typedef __attribute__((ext_vector_type(2))) __bf16 bf16x2;
    bf16x2 r = __builtin_amdgcn_cvt_pk_bf16_f32(a, b);
    return *(uint_t*)&r;
#else
    return (uint_t)f2b(a) | ((uint_t)f2b(b) << 16);
#endif
}

// async global->LDS DMA, 16 B per lane; LDS dest = wave-uniform base + 16*lane
__device__ __forceinline__ void gl2lds16(const ushort_t* g, void* lds) {
    __builtin_amdgcn_global_load_lds(
        (const __attribute__((address_space(1))) void*)g,
        (__attribute__((address_space(3))) void*)lds, 16, 0, 0);
}

// XOR-swizzled frag read from an unpadded [rows][64] bf16 LDS tile:
// physical 16-B chunk p holds logical chunk p ^ (row & 7).
__device__ __forceinline__ short8 frag(const ushort_t* base, int row, int chunk) {
    return *(const short8*)(base + row * 64 + ((chunk ^ (row & 7)) << 3));
}

// ---------------- fp32 -> bf16 convert (pads tail with zeros) ---------------
__global__ __launch_bounds__(256) void conv_bf16(const float* __restrict__ s,
                                                 ushort_t* __restrict__ d,
                                                 int n_valid, int n_total) {
    int i = (blockIdx.x * 256 + threadIdx.x) * 4;
    if (i >= n_total) return;
    float4 v = make_float4(0.f, 0.f, 0.f, 0.f);
    if (i < n_valid) v = *(const float4*)(s + i);   // n_valid multiple of 4
    ushort4 o;
    o.x = f2b(v.x); o.y = f2b(v.y); o.z = f2b(v.z); o.w = f2b(v.w);
    *(ushort4*)(d + i) = o;
}

// ---------------- QKV GEMM: C[m][n] = sum_k A[m][k] W[n][k] -----------------
// RoPE fused into the epilogue (reads the full 64-dim head row from St; the
// rotate-half partner of dim d is d^32 in the same row).
__global__ __launch_bounds__(256, 4) void gemm_qkv(const ushort_t* __restrict__ A,
                                                   const ushort_t* __restrict__ W,
                                                   ushort_t* __restrict__ Q,
                                                   ushort_t* __restrict__ K,
                                                   ushort_t* __restrict__ V,
                                                   const float* __restrict__ sinp,
                                                   const float* __restrict__ cosp) {
    __shared__ uint4 sm[2112];                     // 33792 B
    ushort_t* As = (ushort_t*)sm;                  // [128][64] swizzled
    ushort_t* Bs = As + 128 * 64;                  // [128][64] swizzled
    const int t = threadIdx.x;
    const int w = t >> 6, l = t & 63;
    const int m0 = blockIdx.y * 128, n0 = blockIdx.x * 128;
    const int wm = (w >> 1) * 64, wn = (w & 1) * 64;
    const int srow = (w * 32) + (l >> 3);          // staging row base for i=0
    const int scs = (l & 7) ^ (srow & 7);          // swizzled chunk
    f32x4 acc[4][4] = {};
    for (int k0 = 0; k0 < 1024; k0 += 64) {
        __syncthreads();                           // prev frag reads done
#pragma unroll
        for (int i = 0; i < 4; i++) {
            int row = srow + i * 8;
            gl2lds16(A + (size_t)(m0 + row) * 1024 + k0 + scs * 8,
                     As + (w * 32 + i * 8) * 64);
            gl2lds16(W + (size_t)(n0 + row) * 1024 + k0 + scs * 8,
                     Bs + (w * 32 + i * 8) * 64);
        }
        __syncthreads();                           // drains vmcnt(0): LDS valid
#pragma unroll
        for (int kb = 0; kb < 2; kb++) {
            short8 af[4], bf[4];
#pragma unroll
            for (int mb = 0; mb < 4; mb++)
                af[mb] = frag(As, wm + mb * 16 + (l & 15), kb * 4 + (l >> 4));
#pragma unroll
            for (int nb = 0; nb < 4; nb++)
                bf[nb] = frag(Bs, wn + nb * 16 + (l & 15), kb * 4 + (l >> 4));
#pragma unroll
            for (int mb = 0; mb < 4; mb++)
#pragma unroll
                for (int nb = 0; nb < 4; nb++)
                    acc[mb][nb] = MFMA(af[mb], bf[nb], acc[mb][nb]);
        }
    }
    // ---- epilogue: LDS-staged, coalesced 128-B stores, fused RoPE ----
    __syncthreads();
    ushort_t (*St)[132] = (ushort_t(*)[132])sm;    // 128x132 bf16 = 33792 B
#pragma unroll
    for (int mb = 0; mb < 4; mb++)
#pragma unroll
        for (int r = 0; r < 4; r++)
#pragma unroll
            for (int nb = 0; nb < 4; nb++)
                St[wm + mb * 16 + (l >> 4) * 4 + r][wn + nb * 16 + (l & 15)] =
                    f2b(acc[mb][nb][r]);
    __syncthreads();
#pragma unroll
    for (int it = 0; it < 8; it++) {
        int seg = it * 32 + w * 8 + (l >> 3);
        int mr = seg >> 1, p = seg & 1;
        int m = m0 + mr;
        if (m >= Mv) continue;
        int b = m / 1025, lseq = m - b * 1025;
        int n = n0 + p * 64;
        int which = n >> 10, h = (n >> 6) & 15;
        ushort_t* dst = (which == 0) ? Q : ((which == 1) ? K : V);
        const int d0 = (l & 7) * 8;
        size_t doff = ((size_t)(b * Hv + h) * LpD + lseq) * 64 + d0;
        if (which <= 1 && lseq > 0) {
            // RoPE on patch rows of Q and K
            const ushort_t* rowp = &St[mr][p * 64];
            const float* cw = cosp + (lseq - 1) * 64 + d0;
            const float* sw = sinp + (lseq - 1) * 64 + d0;
            float4 c0 = *(const float4*)cw, c1 = *(const float4*)(cw + 4);
            float4 s0 = *(const float4*)sw, s1 = *(const float4*)(sw + 4);
            float cc[8] = {c0.x, c0.y, c0.z, c0.w, c1.x, c1.y, c1.z, c1.w};
            float ss[8] = {s0.x, s0.y, s0.z, s0.w, s1.x, s1.y, s1.z, s1.w};
            float sgn = (d0 < 32) ? -1.f : 1.f;    // rot = [-t2, t1]
            uint_t ov[4];
#pragma unroll
            for (int jj = 0; jj < 4; jj++) {
                float f0 = b2f(rowp[d0 + jj * 2]);
                float f1 = b2f(rowp[d0 + jj * 2 + 1]);
                float r0 = b2f(rowp[(d0 ^ 32) + jj * 2]) * sgn;
                float r1 = b2f(rowp[(d0 ^ 32) + jj * 2 + 1]) * sgn;
                ov[jj] = pk2(f0 * cc[jj * 2] + r0 * ss[jj * 2],
                             f1 * cc[jj * 2 + 1] + r1 * ss[jj * 2 + 1]);
            }
            *(uint4*)(dst + doff) = *(uint4*)ov;
        } else {
            *(uint4*)(dst + doff) = *(const uint4*)&St[mr][p * 64 + d0];
        }
    }
}

// ---------------- V transpose: [BH][Lp][64] -> [BH][64][Lp] -----------------
__global__ __launch_bounds__(256) void transpose_v(const ushort_t* __restrict__ Vb,
                                                   ushort_t* __restrict__ Vt) {
    __shared__ ushort_t Ts[64][72];
    const int t = threadIdx.x;
    const int l0 = blockIdx.x * 64, bh = blockIdx.y;
#pragma unroll
    for (int i = 0; i < 2; i++) {
        int c = t + 256 * i; int row = c >> 3, cir = c & 7;
        *(uint4*)&Ts[row][cir * 8] =
            *(const uint4*)(Vb + ((size_t)bh * LpD + l0 + row) * 64 + cir * 8);
    }
    __syncthreads();
#pragma unroll
    for (int i = 0; i < 2; i++) {
        int c = t + 256 * i; int d = c >> 3, lg = c & 7;
        short8 v;
#pragma unroll
        for (int j = 0; j < 8; j++) v[j] = (short)Ts[lg * 8 + j][d];
        *(short8*)(Vt + ((size_t)bh * 64 + d) * LpD + l0 + lg * 8) = v;
    }
}

// ---------------- Attention: block = (q-tile 64, bh). Unnormalized exp. -----
// Swapped QK^T (MFMA(K,Q)) so each lane's 4 P-values are consecutive k's of
// one q-row -> single swizzled ds_write_b64 per cb (was 16 ds_write_b16).
// P overlays the dead Q tile: LDS = 40960 B -> 4 blocks/CU. Double-buffered
// K/V DMA with counted vmcnt; setprio(1) around the MFMA cluster.
__global__ __launch_bounds__(256, 4) void attn_mfma(const ushort_t* __restrict__ Qb,
                                                    const ushort_t* __restrict__ Kb,
                                                    const ushort_t* __restrict__ Vt,
                                                    ushort_t* __restrict__ AO) {
    __shared__ ushort_t QP[64 * 64];               // Q tile, then P tile (overlay)
    __shared__ ushort_t Kd[2][64 * 64];            // double-buffered, swizzled
    __shared__ ushort_t Vd[2][64 * 64];
    const int t = threadIdx.x, w = t >> 6, l = t & 63;
    const int qt = blockIdx.x, bh = blockIdx.y;
    const int q0 = qt * 64;
    const size_t kbase = (size_t)bh * LpD * 64;
    const size_t vbase = (size_t)bh * 64 * LpD;
    const int scs = (l & 7) ^ ((l >> 3) & 7);      // swizzled chunk for staging
    const int g = l >> 4;                          // 0..3 lane group
    const int qr = l & 15;                         // q-row within wave tile
    const int q7 = l & 7;                          // row-swizzle key for P

#pragma unroll
    for (int i = 0; i < 2; i++) {                  // Q tile: 16 rows per wave
        int row = w * 16 + i * 8 + (l >> 3);
        gl2lds16(Qb + kbase + (size_t)(q0 + row) * 64 + scs * 8,
                 QP + (w * 16 + i * 8) * 64);
    }
#pragma unroll
    for (int i = 0; i < 2; i++) {                  // K/V tile 0 into buffer 0
        int row = w * 16 + i * 8 + (l >> 3);
        gl2lds16(Kb + kbase + (size_t)row * 64 + scs * 8,
                 Kd[0] + (w * 16 + i * 8) * 64);
        gl2lds16(Vt + vbase + (size_t)row * LpD + scs * 8,
                 Vd[0] + (w * 16 + i * 8) * 64);
    }
    asm volatile("s_waitcnt vmcnt(4)" ::: "memory");   // Q resident (tile0 may fly)
    asm volatile("s_barrier" ::: "memory");
    short8 aq0 = frag(QP, w * 16 + qr, g);
    short8 aq1 = frag(QP, w * 16 + qr, 4 + g);
    // Drain own ds_reads of QP BEFORE the kt=0 barrier: after that barrier
    // other waves overwrite QP with P values (overlay).
    asm volatile("s_waitcnt lgkmcnt(0)" ::: "memory");

    ushort_t* prow = QP + (w * 16 + qr) * 64;      // this lane's P row

    short8 ones;
#pragma unroll
    for (int j = 0; j < 8; j++) ones[j] = (short)0x3F80;   // 1.0 bf16
    f32x4 o[4] = {};
    f32x4 sacc = {};
    const float CE = 0.18033688011112042f;  // log2(e)/8: exp(s/8) = exp2(s*CE)

    for (int kt = 0; kt < 17; kt++) {
        const ushort_t* Ks = Kd[kt & 1];
        const ushort_t* Vs = Vd[kt & 1];
        if (kt < 16) {                             // prefetch tile kt+1
#pragma unroll
            for (int i = 0; i < 2; i++) {
                int row = w * 16 + i * 8 + (l >> 3);
                gl2lds16(Kb + kbase + (size_t)((kt + 1) * 64 + row) * 64 + scs * 8,
                         Kd[(kt + 1) & 1] + (w * 16 + i * 8) * 64);
                gl2lds16(Vt + vbase + (size_t)row * LpD + (kt + 1) * 64 + scs * 8,
                         Vd[(kt + 1) & 1] + (w * 16 + i * 8) * 64);
            }
            asm volatile("s_waitcnt vmcnt(4)" ::: "memory");  // tile kt landed
        } else {
            asm volatile("s_waitcnt vmcnt(0)" ::: "memory");  // last tile
        }
        asm volatile("s_barrier" ::: "memory");    // all waves: tile kt valid
#pragma unroll
        for (int cb = 0; cb < 4; cb++) {
            // swapped operands: D[k][q]; this lane: q = w*16+qr (fixed),
            // k = cb*16 + g*4 + r  (4 consecutive k's)
            short8 bk0 = frag(Ks, cb * 16 + qr, g);
            short8 bk1 = frag(Ks, cb * 16 + qr, 4 + g);
            f32x4 s = {};
            s = MFMA(bk0, aq0, s);
            s = MFMA(bk1, aq1, s);
            float p4[4];
#pragma unroll
            for (int r = 0; r < 4; r++) p4[r] = exp2f(s[r] * CE);
            if (kt == 16) {                        // mask pad keys (>= Lv)
                bool keep0 = (cb == 0) && (g == 0);   // only key 1024 valid
                p4[0] = keep0 ? p4[0] : 0.f;
                p4[1] = 0.f; p4[2] = 0.f; p4[3] = 0.f;
            }
            uint2 pw;
            pw.x = pk2(p4[0], p4[1]);
            pw.y = pk2(p4[2], p4[3]);
            // logical cols cb*16+4g..+3 -> chunk 2cb+(g>>1), half (g&1);
            // physical chunk = logical ^ q7 (row swizzle)
            *(uint2*)(prow + (((2 * cb + (g >> 1)) ^ q7) << 3) + ((g & 1) << 2)) = pw;
        }
        // own-row reads (same 4 lanes wrote this row); compiler inserts lgkm waits
        short8 ap0 = *(const short8*)(prow + ((g ^ q7) << 3));
        short8 ap1 = *(const short8*)(prow + (((4 + g) ^ q7) << 3));
        __builtin_amdgcn_s_setprio(1);
        sacc = MFMA(ap0, ones, sacc);              // exact row-sums of rounded P
        sacc = MFMA(ap1, ones, sacc);
#pragma unroll
        for (int cb = 0; cb < 4; cb++) {
            short8 bv0 = frag(Vs, cb * 16 + qr, g);
            short8 bv1 = frag(Vs, cb * 16 + qr, 4 + g);
            o[cb] = MFMA(ap0, bv0, o[cb]);
            o[cb] = MFMA(ap1, bv1, o[cb]);
        }
        __builtin_amdgcn_s_setprio(0);
        asm volatile("s_barrier" ::: "memory");    // reads of buf[kt&1] done
    }
    const int b = bh >> 4, h = bh & 15;
#pragma unroll
    for (int r = 0; r < 4; r++) {
        int lq = q0 + w * 16 + g * 4 + r;
        if (lq >= Lv) continue;
        float inv = 1.f / sacc[r];
        size_t ob = ((size_t)(b * 1025 + lq)) * 1024 + h * 64;
#pragma unroll
        for (int cb = 0; cb < 4; cb++)
            AO[ob + cb * 16 + qr] = f2b(o[cb][r] * inv);
    }
}

// ---------------- Proj GEMM + bias, fp32 out --------------------------------
__global__ __launch_bounds__(256, 4) void gemm_proj(const ushort_t* __restrict__ A,
                                                    const ushort_t* __restrict__ W,
                                                    const float* __restrict__ bias,
                                                    float* __restrict__ out) {
    __shared__ uint4 sm[2112];                     // 33792 B
    ushort_t* As = (ushort_t*)sm;
    ushort_t* Bs = As + 128 * 64;
    const int t = threadIdx.x;
    const int w = t >> 6, l = t & 63;
    const int m0 = blockIdx.y * 128, n0 = blockIdx.x * 128;
    const int wm = (w >> 1) * 64, wn = (w & 1) * 64;
    const int srow = (w * 32) + (l >> 3);
    const int scs = (l & 7) ^ (srow & 7);
    f32x4 acc[4][4] = {};
    for (int k0 = 0; k0 < 1024; k0 += 64) {
        __syncthreads();
#pragma unroll
        for (int i = 0; i < 4; i++) {
            int row = srow + i * 8;
            gl2lds16(A + (size_t)(m0 + row) * 1024 + k0 + scs * 8,
                     As + (w * 32 + i * 8) * 64);
            gl2lds16(W + (size_t)(n0 + row) * 1024 + k0 + scs * 8,
                     Bs + (w * 32 + i * 8) * 64);
        }
        __syncthreads();
#pragma unroll
        for (int kb = 0; kb < 2; kb++) {
            short8 af[4], bf[4];
#pragma unroll
            for (int mb = 0; mb < 4; mb++)
                af[mb] = frag(As, wm + mb * 16 + (l & 15), kb * 4 + (l >> 4));
#pragma unroll
            for (int nb = 0; nb < 4; nb++)
                bf[nb] = frag(Bs, wn + nb * 16 + (l & 15), kb * 4 + (l >> 4));
#pragma unroll
            for (int mb = 0; mb < 4; mb++)
#pragma unroll
                for (int nb = 0; nb < 4; nb++)
                    acc[mb][nb] = MFMA(af[mb], bf[nb], acc[mb][nb]);
        }
    }
    // ---- epilogue: stage fp32 in 64-row halves, store 512-B rows ----
    float bias4[4];
#pragma unroll
    for (int nb = 0; nb < 4; nb++) bias4[nb] = bias[n0 + wn + nb * 16 + (l & 15)];
    float (*Sf)[132] = (float(*)[132])sm;          // 64x132 fp32 = 33792 B
#pragma unroll
    for (int half = 0; half < 2; half++) {
        __syncthreads();
        if ((w >> 1) == half) {
#pragma unroll
            for (int mb = 0; mb < 4; mb++)
#pragma unroll
                for (int r = 0; r < 4; r++)
#pragma unroll
                    for (int nb = 0; nb < 4; nb++)
                        Sf[mb * 16 + (l >> 4) * 4 + r][wn + nb * 16 + (l & 15)] =
                            acc[mb][nb][r] + bias4[nb];
        }
        __syncthreads();
#pragma unroll
        for (int it = 0; it < 8; it++) {
            int rr = it * 8 + w * 2 + (l >> 5);
            int m = m0 + half * 64 + rr;
            if (m < Mv)
                *(float4*)(out + (size_t)m * 1024 + n0 + (l & 31) * 4) =
                    *(const float4*)&Sf[rr][(l & 31) * 4];
        }
    }
}

extern "C" void kernel_launch(void* const* d_in, const int* in_sizes, int n_in,
                              void* d_out, int out_size, void* d_ws, size_t ws_size,
                              hipStream_t stream) {
    (void)in_sizes; (void)n_in; (void)out_size; (void)ws_size;
    const float* x      = (const float*)d_in[0];
    const float* sinp   = (const float*)d_in[1];
    const float* cosp   = (const float*)d_in[2];
    const float* qkv_w  = (const float*)d_in[3];
    const float* proj_w = (const float*)d_in[4];
    const float* proj_b = (const float*)d_in[5];
    float* out = (float*)d_out;

    const size_t SZH = (size_t)BHv * LpD * 64;     // per Q/K/V tensor (bf16 elems)
    ushort_t* xb  = (ushort_t*)d_ws;               // [Mp][1024]
    ushort_t* qwb = xb + (size_t)Mp * 1024;        // [3072][1024]
    ushort_t* pwb = qwb + (size_t)3072 * 1024;     // [1024][1024]
    ushort_t* Qb  = pwb + (size_t)1024 * 1024;     // [BH][Lp][64]
    ushort_t* Kb  = Qb + SZH;
    ushort_t* Vb  = Kb + SZH;
    ushort_t* Vt  = Vb + SZH;                      // [BH][64][Lp]
    ushort_t* AO  = Vt + SZH;                      // [Mp][1024]

    dim3 blk(256);
    conv_bf16<<<dim3(Mp * 1024 / 1024), blk, 0, stream>>>(x, xb, Mv * 1024, Mp * 1024);
    conv_bf16<<<dim3(3072 * 1024 / 1024), blk, 0, stream>>>(qkv_w, qwb, 3072 * 1024, 3072 * 1024);
    conv_bf16<<<dim3(1024 * 1024 / 1024), blk, 0, stream>>>(proj_w, pwb, 1024 * 1024, 1024 * 1024);
    gemm_qkv<<<dim3(24, 129), blk, 0, stream>>>(xb, qwb, Qb, Kb, Vb, sinp, cosp);
    transpose_v<<<dim3(17, BHv), blk, 0, stream>>>(Vb, Vt);
    attn_mfma<<<dim3(17, BHv), blk, 0, stream>>>(Qb, Kb, Vt, AO);
    gemm_proj<<<dim3(8, 129), blk, 0, stream>>>(AO, pwb, proj_b, out);
}

// Round 5
// 452.888 us; speedup vs baseline: 1.1476x; 1.0761x over previous
//
#include <hip/hip_runtime.h>

typedef unsigned short ushort_t;
typedef unsigned int uint_t;
typedef __attribute__((ext_vector_type(8))) short short8;
typedef __attribute__((ext_vector_type(4))) float f32x4;

#define Bv 16
#define Lv 1025
#define LpD 1088          // 17*64 padded sequence
#define Cv 1024
#define Hv 16
#define BHv 256
#define Mv 16400          // valid rows
#define Mp 16512          // 129*128 padded rows

#define MFMA(a, b, c) __builtin_amdgcn_mfma_f32_16x16x32_bf16(a, b, c, 0, 0, 0)

// f32 -> bf16 RNE via HW pack op (1 VALU op; identical RNE to software path)
__device__ __forceinline__ ushort_t f2b(float x) {
    uint_t r;
    asm("v_cvt_pk_bf16_f32 %0, %1, %1" : "=v"(r) : "v"(x));
    return (ushort_t)r;
}
__device__ __forceinline__ float b2f(ushort_t v) {
    return __uint_as_float(((uint_t)v) << 16);
}
// packed f32x2 -> bf16x2 (1 VALU op; no builtin on gfx950 -> inline asm)
__device__ __forceinline__ uint_t pk2(float a, float b) {
    uint_t r;
    asm("v_cvt_pk_bf16_f32 %0, %1, %2" : "=v"(r) : "v"(a), "v"(b));
    return r;
}
// raw 2^x (1 trans op; valid for the normal range our scores occupy)
__device__ __forceinline__ float fexp2(float x) {
    float r;
    asm("v_exp_f32 %0, %1" : "=v"(r) : "v"(x));
    return r;
}

// async global->LDS DMA, 16 B per lane; LDS dest = wave-uniform base + 16*lane
__device__ __forceinline__ void gl2lds16(const ushort_t* g, void* lds) {
    __builtin_amdgcn_global_load_lds(
        (const __attribute__((address_space(1))) void*)g,
        (__attribute__((address_space(3))) void*)lds, 16, 0, 0);
}

// XOR-swizzled frag read from an unpadded [rows][64] bf16 LDS tile:
// physical 16-B chunk p holds logical chunk p ^ (row & 7).
__device__ __forceinline__ short8 frag(const ushort_t* base, int row, int chunk) {
    return *(const short8*)(base + row * 64 + ((chunk ^ (row & 7)) << 3));
}

// ---------------- fp32 -> bf16 convert (pads tail with zeros) ---------------
__global__ __launch_bounds__(256) void conv_bf16(const float* __restrict__ s,
                                                 ushort_t* __restrict__ d,
                                                 int n_valid, int n_total) {
    int i = (blockIdx.x * 256 + threadIdx.x) * 4;
    if (i >= n_total) return;
    float4 v = make_float4(0.f, 0.f, 0.f, 0.f);
    if (i < n_valid) v = *(const float4*)(s + i);   // n_valid multiple of 4
    uint2 o;
    o.x = pk2(v.x, v.y);
    o.y = pk2(v.z, v.w);
    *(uint2*)(d + i) = o;
}

// ---------------- QKV GEMM: C[m][n] = sum_k A[m][k] W[n][k] -----------------
// RoPE fused into the epilogue (reads the full 64-dim head row from St; the
// rotate-half partner of dim d is d^32 in the same row).
__global__ __launch_bounds__(256, 4) void gemm_qkv(const ushort_t* __restrict__ A,
                                                   const ushort_t* __restrict__ W,
                                                   ushort_t* __restrict__ Q,
                                                   ushort_t* __restrict__ K,
                                                   ushort_t* __restrict__ V,
                                                   const float* __restrict__ sinp,
                                                   const float* __restrict__ cosp) {
    __shared__ uint4 sm[2112];                     // 33792 B
    ushort_t* As = (ushort_t*)sm;                  // [128][64] swizzled
    ushort_t* Bs = As + 128 * 64;                  // [128][64] swizzled
    const int t = threadIdx.x;
    const int w = t >> 6, l = t & 63;
    const int m0 = blockIdx.y * 128, n0 = blockIdx.x * 128;
    const int wm = (w >> 1) * 64, wn = (w & 1) * 64;
    const int srow = (w * 32) + (l >> 3);          // staging row base for i=0
    const int scs = (l & 7) ^ (srow & 7);          // swizzled chunk
    f32x4 acc[4][4] = {};
    for (int k0 = 0; k0 < 1024; k0 += 64) {
        __syncthreads();                           // prev frag reads done
#pragma unroll
        for (int i = 0; i < 4; i++) {
            int row = srow + i * 8;
            gl2lds16(A + (size_t)(m0 + row) * 1024 + k0 + scs * 8,
                     As + (w * 32 + i * 8) * 64);
            gl2lds16(W + (size_t)(n0 + row) * 1024 + k0 + scs * 8,
                     Bs + (w * 32 + i * 8) * 64);
        }
        __syncthreads();                           // drains vmcnt(0): LDS valid
#pragma unroll
        for (int kb = 0; kb < 2; kb++) {
            short8 af[4], bf[4];
#pragma unroll
            for (int mb = 0; mb < 4; mb++)
                af[mb] = frag(As, wm + mb * 16 + (l & 15), kb * 4 + (l >> 4));
#pragma unroll
            for (int nb = 0; nb < 4; nb++)
                bf[nb] = frag(Bs, wn + nb * 16 + (l & 15), kb * 4 + (l >> 4));
#pragma unroll
            for (int mb = 0; mb < 4; mb++)
#pragma unroll
                for (int nb = 0; nb < 4; nb++)
                    acc[mb][nb] = MFMA(af[mb], bf[nb], acc[mb][nb]);
        }
    }
    // ---- epilogue: LDS-staged, coalesced 128-B stores, fused RoPE ----
    __syncthreads();
    ushort_t (*St)[132] = (ushort_t(*)[132])sm;    // 128x132 bf16 = 33792 B
#pragma unroll
    for (int mb = 0; mb < 4; mb++)
#pragma unroll
        for (int r = 0; r < 4; r++)
#pragma unroll
            for (int nb = 0; nb < 4; nb++)
                St[wm + mb * 16 + (l >> 4) * 4 + r][wn + nb * 16 + (l & 15)] =
                    f2b(acc[mb][nb][r]);
    __syncthreads();
#pragma unroll
    for (int it = 0; it < 8; it++) {
        int seg = it * 32 + w * 8 + (l >> 3);
        int mr = seg >> 1, p = seg & 1;
        int m = m0 + mr;
        if (m >= Mv) continue;
        int b = m / 1025, lseq = m - b * 1025;
        int n = n0 + p * 64;
        int which = n >> 10, h = (n >> 6) & 15;
        ushort_t* dst = (which == 0) ? Q : ((which == 1) ? K : V);
        const int d0 = (l & 7) * 8;
        size_t doff = ((size_t)(b * Hv + h) * LpD + lseq) * 64 + d0;
        if (which <= 1 && lseq > 0) {
            // RoPE on patch rows of Q and K
            const ushort_t* rowp = &St[mr][p * 64];
            const float* cw = cosp + (lseq - 1) * 64 + d0;
            const float* sw = sinp + (lseq - 1) * 64 + d0;
            float4 c0 = *(const float4*)cw, c1 = *(const float4*)(cw + 4);
            float4 s0 = *(const float4*)sw, s1 = *(const float4*)(sw + 4);
            float cc[8] = {c0.x, c0.y, c0.z, c0.w, c1.x, c1.y, c1.z, c1.w};
            float ss[8] = {s0.x, s0.y, s0.z, s0.w, s1.x, s1.y, s1.z, s1.w};
            float sgn = (d0 < 32) ? -1.f : 1.f;    // rot = [-t2, t1]
            uint_t ov[4];
#pragma unroll
            for (int jj = 0; jj < 4; jj++) {
                float f0 = b2f(rowp[d0 + jj * 2]);
                float f1 = b2f(rowp[d0 + jj * 2 + 1]);
                float r0 = b2f(rowp[(d0 ^ 32) + jj * 2]) * sgn;
                float r1 = b2f(rowp[(d0 ^ 32) + jj * 2 + 1]) * sgn;
                ov[jj] = pk2(f0 * cc[jj * 2] + r0 * ss[jj * 2],
                             f1 * cc[jj * 2 + 1] + r1 * ss[jj * 2 + 1]);
            }
            *(uint4*)(dst + doff) = *(uint4*)ov;
        } else {
            *(uint4*)(dst + doff) = *(const uint4*)&St[mr][p * 64 + d0];
        }
    }
}

// ---------------- V transpose: [BH][Lp][64] -> [BH][64][Lp] -----------------
__global__ __launch_bounds__(256) void transpose_v(const ushort_t* __restrict__ Vb,
                                                   ushort_t* __restrict__ Vt) {
    __shared__ ushort_t Ts[64][72];
    const int t = threadIdx.x;
    const int l0 = blockIdx.x * 64, bh = blockIdx.y;
#pragma unroll
    for (int i = 0; i < 2; i++) {
        int c = t + 256 * i; int row = c >> 3, cir = c & 7;
        *(uint4*)&Ts[row][cir * 8] =
            *(const uint4*)(Vb + ((size_t)bh * LpD + l0 + row) * 64 + cir * 8);
    }
    __syncthreads();
#pragma unroll
    for (int i = 0; i < 2; i++) {
        int c = t + 256 * i; int d = c >> 3, lg = c & 7;
        short8 v;
#pragma unroll
        for (int j = 0; j < 8; j++) v[j] = (short)Ts[lg * 8 + j][d];
        *(short8*)(Vt + ((size_t)bh * 64 + d) * LpD + l0 + lg * 8) = v;
    }
}

// ---------------- Attention: block = (q-tile 64, bh). Unnormalized exp. -----
// Swapped QK^T (MFMA(K,Q)) so each lane's 4 P-values are consecutive k's of
// one q-row -> single swizzled ds_write_b64 per cb. P overlays the dead Q
// tile: LDS = 40960 B -> 4 blocks/CU. Double-buffered K/V DMA with counted
// vmcnt; setprio(1) around the MFMA cluster. exp/cvt via raw HW ops.
__global__ __launch_bounds__(256, 4) void attn_mfma(const ushort_t* __restrict__ Qb,
                                                    const ushort_t* __restrict__ Kb,
                                                    const ushort_t* __restrict__ Vt,
                                                    ushort_t* __restrict__ AO) {
    __shared__ ushort_t QP[64 * 64];               // Q tile, then P tile (overlay)
    __shared__ ushort_t Kd[2][64 * 64];            // double-buffered, swizzled
    __shared__ ushort_t Vd[2][64 * 64];
    const int t = threadIdx.x, w = t >> 6, l = t & 63;
    const int qt = blockIdx.x, bh = blockIdx.y;
    const int q0 = qt * 64;
    const size_t kbase = (size_t)bh * LpD * 64;
    const size_t vbase = (size_t)bh * 64 * LpD;
    const int scs = (l & 7) ^ ((l >> 3) & 7);      // swizzled chunk for staging
    const int g = l >> 4;                          // 0..3 lane group
    const int qr = l & 15;                         // q-row within wave tile
    const int q7 = l & 7;                          // row-swizzle key for P

#pragma unroll
    for (int i = 0; i < 2; i++) {                  // Q tile: 16 rows per wave
        int row = w * 16 + i * 8 + (l >> 3);
        gl2lds16(Qb + kbase + (size_t)(q0 + row) * 64 + scs * 8,
                 QP + (w * 16 + i * 8) * 64);
    }
#pragma unroll
    for (int i = 0; i < 2; i++) {                  // K/V tile 0 into buffer 0
        int row = w * 16 + i * 8 + (l >> 3);
        gl2lds16(Kb + kbase + (size_t)row * 64 + scs * 8,
                 Kd[0] + (w * 16 + i * 8) * 64);
        gl2lds16(Vt + vbase + (size_t)row * LpD + scs * 8,
                 Vd[0] + (w * 16 + i * 8) * 64);
    }
    asm volatile("s_waitcnt vmcnt(4)" ::: "memory");   // Q resident (tile0 may fly)
    asm volatile("s_barrier" ::: "memory");
    short8 aq0 = frag(QP, w * 16 + qr, g);
    short8 aq1 = frag(QP, w * 16 + qr, 4 + g);
    // Drain own ds_reads of QP BEFORE the kt=0 barrier: after that barrier
    // other waves overwrite QP with P values (overlay).
    asm volatile("s_waitcnt lgkmcnt(0)" ::: "memory");

    ushort_t* prow = QP + (w * 16 + qr) * 64;      // this lane's P row

    short8 ones;
#pragma unroll
    for (int j = 0; j < 8; j++) ones[j] = (short)0x3F80;   // 1.0 bf16
    f32x4 o[4] = {};
    f32x4 sacc = {};
    const float CE = 0.18033688011112042f;  // log2(e)/8: exp(s/8) = exp2(s*CE)

    for (int kt = 0; kt < 17; kt++) {
        const ushort_t* Ks = Kd[kt & 1];
        const ushort_t* Vs = Vd[kt & 1];
        if (kt < 16) {                             // prefetch tile kt+1
#pragma unroll
            for (int i = 0; i < 2; i++) {
                int row = w * 16 + i * 8 + (l >> 3);
                gl2lds16(Kb + kbase + (size_t)((kt + 1) * 64 + row) * 64 + scs * 8,
                         Kd[(kt + 1) & 1] + (w * 16 + i * 8) * 64);
                gl2lds16(Vt + vbase + (size_t)row * LpD + (kt + 1) * 64 + scs * 8,
                         Vd[(kt + 1) & 1] + (w * 16 + i * 8) * 64);
            }
            asm volatile("s_waitcnt vmcnt(4)" ::: "memory");  // tile kt landed
        } else {
            asm volatile("s_waitcnt vmcnt(0)" ::: "memory");  // last tile
        }
        asm volatile("s_barrier" ::: "memory");    // all waves: tile kt valid
#pragma unroll
        for (int cb = 0; cb < 4; cb++) {
            // swapped operands: D[k][q]; this lane: q = w*16+qr (fixed),
            // k = cb*16 + g*4 + r  (4 consecutive k's)
            short8 bk0 = frag(Ks, cb * 16 + qr, g);
            short8 bk1 = frag(Ks, cb * 16 + qr, 4 + g);
            f32x4 s = {};
            s = MFMA(bk0, aq0, s);
            s = MFMA(bk1, aq1, s);
            float p4[4];
#pragma unroll
            for (int r = 0; r < 4; r++) p4[r] = fexp2(s[r] * CE);
            if (kt == 16) {                        // mask pad keys (>= Lv)
                bool keep0 = (cb == 0) && (g == 0);   // only key 1024 valid
                p4[0] = keep0 ? p4[0] : 0.f;
                p4[1] = 0.f; p4[2] = 0.f; p4[3] = 0.f;
            }
            uint2 pw;
            pw.x = pk2(p4[0], p4[1]);
            pw.y = pk2(p4[2], p4[3]);
            // logical cols cb*16+4g..+3 -> chunk 2cb+(g>>1), half (g&1);
            // physical chunk = logical ^ q7 (row swizzle)
            *(uint2*)(prow + (((2 * cb + (g >> 1)) ^ q7) << 3) + ((g & 1) << 2)) = pw;
        }
        // own-row reads (same 4 lanes wrote this row); compiler inserts lgkm waits
        short8 ap0 = *(const short8*)(prow + ((g ^ q7) << 3));
        short8 ap1 = *(const short8*)(prow + (((4 + g) ^ q7) << 3));
        __builtin_amdgcn_s_setprio(1);
        sacc = MFMA(ap0, ones, sacc);              // exact row-sums of rounded P
        sacc = MFMA(ap1, ones, sacc);
#pragma unroll
        for (int cb = 0; cb < 4; cb++) {
            short8 bv0 = frag(Vs, cb * 16 + qr, g);
            short8 bv1 = frag(Vs, cb * 16 + qr, 4 + g);
            o[cb] = MFMA(ap0, bv0, o[cb]);
            o[cb] = MFMA(ap1, bv1, o[cb]);
        }
        __builtin_amdgcn_s_setprio(0);
        asm volatile("s_barrier" ::: "memory");    // reads of buf[kt&1] done
    }
    const int b = bh >> 4, h = bh & 15;
#pragma unroll
    for (int r = 0; r < 4; r++) {
        int lq = q0 + w * 16 + g * 4 + r;
        if (lq >= Lv) continue;
        float inv = 1.f / sacc[r];
        size_t ob = ((size_t)(b * 1025 + lq)) * 1024 + h * 64;
#pragma unroll
        for (int cb = 0; cb < 4; cb++)
            AO[ob + cb * 16 + qr] = f2b(o[cb][r] * inv);
    }
}

// ---------------- Proj GEMM + bias, fp32 out --------------------------------
__global__ __launch_bounds__(256, 4) void gemm_proj(const ushort_t* __restrict__ A,
                                                    const ushort_t* __restrict__ W,
                                                    const float* __restrict__ bias,
                                                    float* __restrict__ out) {
    __shared__ uint4 sm[2112];                     // 33792 B
    ushort_t* As = (ushort_t*)sm;
    ushort_t* Bs = As + 128 * 64;
    const int t = threadIdx.x;
    const int w = t >> 6, l = t & 63;
    const int m0 = blockIdx.y * 128, n0 = blockIdx.x * 128;
    const int wm = (w >> 1) * 64, wn = (w & 1) * 64;
    const int srow = (w * 32) + (l >> 3);
    const int scs = (l & 7) ^ (srow & 7);
    f32x4 acc[4][4] = {};
    for (int k0 = 0; k0 < 1024; k0 += 64) {
        __syncthreads();
#pragma unroll
        for (int i = 0; i < 4; i++) {
            int row = srow + i * 8;
            gl2lds16(A + (size_t)(m0 + row) * 1024 + k0 + scs * 8,
                     As + (w * 32 + i * 8) * 64);
            gl2lds16(W + (size_t)(n0 + row) * 1024 + k0 + scs * 8,
                     Bs + (w * 32 + i * 8) * 64);
        }
        __syncthreads();
#pragma unroll
        for (int kb = 0; kb < 2; kb++) {
            short8 af[4], bf[4];
#pragma unroll
            for (int mb = 0; mb < 4; mb++)
                af[mb] = frag(As, wm + mb * 16 + (l & 15), kb * 4 + (l >> 4));
#pragma unroll
            for (int nb = 0; nb < 4; nb++)
                bf[nb] = frag(Bs, wn + nb * 16 + (l & 15), kb * 4 + (l >> 4));
#pragma unroll
            for (int mb = 0; mb < 4; mb++)
#pragma unroll
                for (int nb = 0; nb < 4; nb++)
                    acc[mb][nb] = MFMA(af[mb], bf[nb], acc[mb][nb]);
        }
    }
    // ---- epilogue: stage fp32 in 64-row halves, store 512-B rows ----
    float bias4[4];
#pragma unroll
    for (int nb = 0; nb < 4; nb++) bias4[nb] = bias[n0 + wn + nb * 16 + (l & 15)];
    float (*Sf)[132] = (float(*)[132])sm;          // 64x132 fp32 = 33792 B
#pragma unroll
    for (int half = 0; half < 2; half++) {
        __syncthreads();
        if ((w >> 1) == half) {
#pragma unroll
            for (int mb = 0; mb < 4; mb++)
#pragma unroll
                for (int r = 0; r < 4; r++)
#pragma unroll
                    for (int nb = 0; nb < 4; nb++)
                        Sf[mb * 16 + (l >> 4) * 4 + r][wn + nb * 16 + (l & 15)] =
                            acc[mb][nb][r] + bias4[nb];
        }
        __syncthreads();
#pragma unroll
        for (int it = 0; it < 8; it++) {
            int rr = it * 8 + w * 2 + (l >> 5);
            int m = m0 + half * 64 + rr;
            if (m < Mv)
                *(float4*)(out + (size_t)m * 1024 + n0 + (l & 31) * 4) =
                    *(const float4*)&Sf[rr][(l & 31) * 4];
        }
    }
}

extern "C" void kernel_launch(void* const* d_in, const int* in_sizes, int n_in,
                              void* d_out, int out_size, void* d_ws, size_t ws_size,
                              hipStream_t stream) {
    (void)in_sizes; (void)n_in; (void)out_size; (void)ws_size;
    const float* x      = (const float*)d_in[0];
    const float* sinp   = (const float*)d_in[1];
    const float* cosp   = (const float*)d_in[2];
    const float* qkv_w  = (const float*)d_in[3];
    const float* proj_w = (const float*)d_in[4];
    const float* proj_b = (const float*)d_in[5];
    float* out = (float*)d_out;

    const size_t SZH = (size_t)BHv * LpD * 64;     // per Q/K/V tensor (bf16 elems)
    ushort_t* xb  = (ushort_t*)d_ws;               // [Mp][1024]
    ushort_t* qwb = xb + (size_t)Mp * 1024;        // [3072][1024]
    ushort_t* pwb = qwb + (size_t)3072 * 1024;     // [1024][1024]
    ushort_t* Qb  = pwb + (size_t)1024 * 1024;     // [BH][Lp][64]
    ushort_t* Kb  = Qb + SZH;
    ushort_t* Vb  = Kb + SZH;
    ushort_t* Vt  = Vb + SZH;                      // [BH][64][Lp]
    ushort_t* AO  = Vt + SZH;                      // [Mp][1024]

    dim3 blk(256);
    conv_bf16<<<dim3(Mp * 1024 / 1024), blk, 0, stream>>>(x, xb, Mv * 1024, Mp * 1024);
    conv_bf16<<<dim3(3072 * 1024 / 1024), blk, 0, stream>>>(qkv_w, qwb, 3072 * 1024, 3072 * 1024);
    conv_bf16<<<dim3(1024 * 1024 / 1024), blk, 0, stream>>>(proj_w, pwb, 1024 * 1024, 1024 * 1024);
    gemm_qkv<<<dim3(24, 129), blk, 0, stream>>>(xb, qwb, Qb, Kb, Vb, sinp, cosp);
    transpose_v<<<dim3(17, BHv), blk, 0, stream>>>(Vb, Vt);
    attn_mfma<<<dim3(17, BHv), blk, 0, stream>>>(Qb, Kb, Vt, AO);
    gemm_proj<<<dim3(8, 129), blk, 0, stream>>>(AO, pwb, proj_b, out);
}

// Round 8
// 438.836 us; speedup vs baseline: 1.1843x; 1.0320x over previous
//
#include <hip/hip_runtime.h>

typedef unsigned short ushort_t;
typedef unsigned int uint_t;
typedef __attribute__((ext_vector_type(8))) short short8;
typedef __attribute__((ext_vector_type(4))) float f32x4;

#define Bv 16
#define Lv 1025
#define LpD 1088          // 17*64 padded sequence
#define Cv 1024
#define Hv 16
#define BHv 256
#define Mv 16400          // valid rows
#define Mp 16512          // 129*128 padded rows

#define MFMA(a, b, c) __builtin_amdgcn_mfma_f32_16x16x32_bf16(a, b, c, 0, 0, 0)

// f32 -> bf16 RNE via HW pack op (1 VALU op; identical RNE to software path)
__device__ __forceinline__ ushort_t f2b(float x) {
    uint_t r;
    asm("v_cvt_pk_bf16_f32 %0, %1, %1" : "=v"(r) : "v"(x));
    return (ushort_t)r;
}
__device__ __forceinline__ float b2f(ushort_t v) {
    return __uint_as_float(((uint_t)v) << 16);
}
// packed f32x2 -> bf16x2 (1 VALU op; no builtin on gfx950 -> inline asm)
__device__ __forceinline__ uint_t pk2(float a, float b) {
    uint_t r;
    asm("v_cvt_pk_bf16_f32 %0, %1, %2" : "=v"(r) : "v"(a), "v"(b));
    return r;
}
// raw 2^x (1 trans op; valid for the normal range our scores occupy)
__device__ __forceinline__ float fexp2(float x) {
    float r;
    asm("v_exp_f32 %0, %1" : "=v"(r) : "v"(x));
    return r;
}

// async global->LDS DMA, 16 B per lane; LDS dest = wave-uniform base + 16*lane
__device__ __forceinline__ void gl2lds16(const ushort_t* g, void* lds) {
    __builtin_amdgcn_global_load_lds(
        (const __attribute__((address_space(1))) void*)g,
        (__attribute__((address_space(3))) void*)lds, 16, 0, 0);
}

// XOR-swizzled frag read from an unpadded [rows][64] bf16 LDS tile:
// physical 16-B chunk p holds logical chunk p ^ (row & 7).
__device__ __forceinline__ short8 frag(const ushort_t* base, int row, int chunk) {
    return *(const short8*)(base + row * 64 + ((chunk ^ (row & 7)) << 3));
}

// ---------------- fp32 -> bf16 convert (pads tail with zeros) ---------------
__global__ __launch_bounds__(256) void conv_bf16(const float* __restrict__ s,
                                                 ushort_t* __restrict__ d,
                                                 int n_valid, int n_total) {
    int i = (blockIdx.x * 256 + threadIdx.x) * 4;
    if (i >= n_total) return;
    float4 v = make_float4(0.f, 0.f, 0.f, 0.f);
    if (i < n_valid) v = *(const float4*)(s + i);   // n_valid multiple of 4
    uint2 o;
    o.x = pk2(v.x, v.y);
    o.y = pk2(v.z, v.w);
    *(uint2*)(d + i) = o;
}

// ---------------- QKV GEMM: C[m][n] = sum_k A[m][k] W[n][k] -----------------
// RoPE fused into the epilogue (reads the full 64-dim head row from St; the
// rotate-half partner of dim d is d^32 in the same row).
__global__ __launch_bounds__(256, 4) void gemm_qkv(const ushort_t* __restrict__ A,
                                                   const ushort_t* __restrict__ W,
                                                   ushort_t* __restrict__ Q,
                                                   ushort_t* __restrict__ K,
                                                   ushort_t* __restrict__ V,
                                                   const float* __restrict__ sinp,
                                                   const float* __restrict__ cosp) {
    __shared__ uint4 sm[2112];                     // 33792 B
    ushort_t* As = (ushort_t*)sm;                  // [128][64] swizzled
    ushort_t* Bs = As + 128 * 64;                  // [128][64] swizzled
    const int t = threadIdx.x;
    const int w = t >> 6, l = t & 63;
    const int m0 = blockIdx.y * 128, n0 = blockIdx.x * 128;
    const int wm = (w >> 1) * 64, wn = (w & 1) * 64;
    const int srow = (w * 32) + (l >> 3);          // staging row base for i=0
    const int scs = (l & 7) ^ (srow & 7);          // swizzled chunk
    f32x4 acc[4][4] = {};
    for (int k0 = 0; k0 < 1024; k0 += 64) {
        __syncthreads();                           // prev frag reads done
#pragma unroll
        for (int i = 0; i < 4; i++) {
            int row = srow + i * 8;
            gl2lds16(A + (size_t)(m0 + row) * 1024 + k0 + scs * 8,
                     As + (w * 32 + i * 8) * 64);
            gl2lds16(W + (size_t)(n0 + row) * 1024 + k0 + scs * 8,
                     Bs + (w * 32 + i * 8) * 64);
        }
        __syncthreads();                           // drains vmcnt(0): LDS valid
#pragma unroll
        for (int kb = 0; kb < 2; kb++) {
            short8 af[4], bf[4];
#pragma unroll
            for (int mb = 0; mb < 4; mb++)
                af[mb] = frag(As, wm + mb * 16 + (l & 15), kb * 4 + (l >> 4));
#pragma unroll
            for (int nb = 0; nb < 4; nb++)
                bf[nb] = frag(Bs, wn + nb * 16 + (l & 15), kb * 4 + (l >> 4));
#pragma unroll
            for (int mb = 0; mb < 4; mb++)
#pragma unroll
                for (int nb = 0; nb < 4; nb++)
                    acc[mb][nb] = MFMA(af[mb], bf[nb], acc[mb][nb]);
        }
    }
    // ---- epilogue: LDS-staged, coalesced 128-B stores, fused RoPE ----
    __syncthreads();
    ushort_t (*St)[132] = (ushort_t(*)[132])sm;    // 128x132 bf16 = 33792 B
#pragma unroll
    for (int mb = 0; mb < 4; mb++)
#pragma unroll
        for (int r = 0; r < 4; r++)
#pragma unroll
            for (int nb = 0; nb < 4; nb++)
                St[wm + mb * 16 + (l >> 4) * 4 + r][wn + nb * 16 + (l & 15)] =
                    f2b(acc[mb][nb][r]);
    __syncthreads();
#pragma unroll
    for (int it = 0; it < 8; it++) {
        int seg = it * 32 + w * 8 + (l >> 3);
        int mr = seg >> 1, p = seg & 1;
        int m = m0 + mr;
        if (m >= Mv) continue;
        int b = m / 1025, lseq = m - b * 1025;
        int n = n0 + p * 64;
        int which = n >> 10, h = (n >> 6) & 15;
        ushort_t* dst = (which == 0) ? Q : ((which == 1) ? K : V);
        const int d0 = (l & 7) * 8;
        size_t doff = ((size_t)(b * Hv + h) * LpD + lseq) * 64 + d0;
        if (which <= 1 && lseq > 0) {
            // RoPE on patch rows of Q and K
            const ushort_t* rowp = &St[mr][p * 64];
            const float* cw = cosp + (lseq - 1) * 64 + d0;
            const float* sw = sinp + (lseq - 1) * 64 + d0;
            float4 c0 = *(const float4*)cw, c1 = *(const float4*)(cw + 4);
            float4 s0 = *(const float4*)sw, s1 = *(const float4*)(sw + 4);
            float cc[8] = {c0.x, c0.y, c0.z, c0.w, c1.x, c1.y, c1.z, c1.w};
            float ss[8] = {s0.x, s0.y, s0.z, s0.w, s1.x, s1.y, s1.z, s1.w};
            float sgn = (d0 < 32) ? -1.f : 1.f;    // rot = [-t2, t1]
            uint_t ov[4];
#pragma unroll
            for (int jj = 0; jj < 4; jj++) {
                float f0 = b2f(rowp[d0 + jj * 2]);
                float f1 = b2f(rowp[d0 + jj * 2 + 1]);
                float r0 = b2f(rowp[(d0 ^ 32) + jj * 2]) * sgn;
                float r1 = b2f(rowp[(d0 ^ 32) + jj * 2 + 1]) * sgn;
                ov[jj] = pk2(f0 * cc[jj * 2] + r0 * ss[jj * 2],
                             f1 * cc[jj * 2 + 1] + r1 * ss[jj * 2 + 1]);
            }
            *(uint4*)(dst + doff) = *(uint4*)ov;
        } else {
            *(uint4*)(dst + doff) = *(const uint4*)&St[mr][p * 64 + d0];
        }
    }
}

// ---------------- V transpose: [BH][Lp][64] -> [BH][64][Lp] -----------------
// Source rows >= Lv are never written by gemm_qkv (stale workspace). They are
// multiplied by P==0 in attn's last tile; 0*Inf/NaN = NaN would contaminate
// valid rows, so substitute exact zeros here (content-independent safety).
__global__ __launch_bounds__(256) void transpose_v(const ushort_t* __restrict__ Vb,
                                                   ushort_t* __restrict__ Vt) {
    __shared__ ushort_t Ts[64][72];
    const int t = threadIdx.x;
    const int l0 = blockIdx.x * 64, bh = blockIdx.y;
#pragma unroll
    for (int i = 0; i < 2; i++) {
        int c = t + 256 * i; int row = c >> 3, cir = c & 7;
        uint4 v = make_uint4(0u, 0u, 0u, 0u);
        if (l0 + row < Lv)
            v = *(const uint4*)(Vb + ((size_t)bh * LpD + l0 + row) * 64 + cir * 8);
        *(uint4*)&Ts[row][cir * 8] = v;
    }
    __syncthreads();
#pragma unroll
    for (int i = 0; i < 2; i++) {
        int c = t + 256 * i; int d = c >> 3, lg = c & 7;
        short8 v;
#pragma unroll
        for (int j = 0; j < 8; j++) v[j] = (short)Ts[lg * 8 + j][d];
        *(short8*)(Vt + ((size_t)bh * 64 + d) * LpD + l0 + lg * 8) = v;
    }
}

// ---------------- Attention: block = (q-tile 64, bh). Unnormalized exp. -----
// Round-5 structure (verified passing). Swapped QK^T (MFMA(K,Q)); P overlays
// the dead Q tile (LDS 40960 B -> 4 blocks/CU); double-buffered K/V DMA with
// counted vmcnt; setprio around the MFMA cluster; raw v_exp/cvt_pk ops.
// NEW: XCD-aware block swizzle (T1): 4352 blocks = 8 XCDs x 544; give each
// XCD contiguous nid -> all 17 q-tiles of a head land on one XCD's L2.
__global__ __launch_bounds__(256, 4) void attn_mfma(const ushort_t* __restrict__ Qb,
                                                    const ushort_t* __restrict__ Kb,
                                                    const ushort_t* __restrict__ Vt,
                                                    ushort_t* __restrict__ AO) {
    __shared__ ushort_t QP[64 * 64];               // Q tile, then P tile (overlay)
    __shared__ ushort_t Kd[2][64 * 64];            // double-buffered, swizzled
    __shared__ ushort_t Vd[2][64 * 64];
    const int t = threadIdx.x, w = t >> 6, l = t & 63;
    const int wg = blockIdx.x;                     // 0..4351, 1-D grid
    const int nid = (wg & 7) * 544 + (wg >> 3);    // bijective XCD swizzle
    const int bh = nid / 17, qt = nid - bh * 17;
    const int q0 = qt * 64;
    const size_t kbase = (size_t)bh * LpD * 64;
    const size_t vbase = (size_t)bh * 64 * LpD;
    const int scs = (l & 7) ^ ((l >> 3) & 7);      // swizzled chunk for staging
    const int g = l >> 4;                          // 0..3 lane group
    const int qr = l & 15;                         // q-row / d-col within tile
    const int q7 = l & 7;                          // row-swizzle key for P

#pragma unroll
    for (int i = 0; i < 2; i++) {                  // Q tile: 16 rows per wave
        int row = w * 16 + i * 8 + (l >> 3);
        gl2lds16(Qb + kbase + (size_t)(q0 + row) * 64 + scs * 8,
                 QP + (w * 16 + i * 8) * 64);
    }
#pragma unroll
    for (int i = 0; i < 2; i++) {                  // K/V tile 0 into buffer 0
        int row = w * 16 + i * 8 + (l >> 3);
        gl2lds16(Kb + kbase + (size_t)row * 64 + scs * 8,
                 Kd[0] + (w * 16 + i * 8) * 64);
        gl2lds16(Vt + vbase + (size_t)row * LpD + scs * 8,
                 Vd[0] + (w * 16 + i * 8) * 64);
    }
    asm volatile("s_waitcnt vmcnt(4)" ::: "memory");   // Q resident (tile0 may fly)
    asm volatile("s_barrier" ::: "memory");
    short8 aq0 = frag(QP, w * 16 + qr, g);
    short8 aq1 = frag(QP, w * 16 + qr, 4 + g);
    // Drain own ds_reads of QP BEFORE the kt=0 barrier: after that barrier
    // other waves overwrite QP with P values (overlay).
    asm volatile("s_waitcnt lgkmcnt(0)" ::: "memory");

    ushort_t* prow = QP + (w * 16 + qr) * 64;      // this lane's P row

    short8 ones;
#pragma unroll
    for (int j = 0; j < 8; j++) ones[j] = (short)0x3F80;   // 1.0 bf16
    f32x4 o[4] = {};
    f32x4 sacc = {};
    const float CE = 0.18033688011112042f;  // log2(e)/8: exp(s/8) = exp2(s*CE)

    for (int kt = 0; kt < 17; kt++) {
        const ushort_t* Ks = Kd[kt & 1];
        const ushort_t* Vs = Vd[kt & 1];
        if (kt < 16) {                             // prefetch tile kt+1
#pragma unroll
            for (int i = 0; i < 2; i++) {
                int row = w * 16 + i * 8 + (l >> 3);
                gl2lds16(Kb + kbase + (size_t)((kt + 1) * 64 + row) * 64 + scs * 8,
                         Kd[(kt + 1) & 1] + (w * 16 + i * 8) * 64);
                gl2lds16(Vt + vbase + (size_t)row * LpD + (kt + 1) * 64 + scs * 8,
                         Vd[(kt + 1) & 1] + (w * 16 + i * 8) * 64);
            }
            asm volatile("s_waitcnt vmcnt(4)" ::: "memory");  // tile kt landed
        } else {
            asm volatile("s_waitcnt vmcnt(0)" ::: "memory");  // last tile
        }
        asm volatile("s_barrier" ::: "memory");    // all waves: tile kt valid
#pragma unroll
        for (int cb = 0; cb < 4; cb++) {
            // swapped operands: D[k][q]; this lane: q = w*16+qr (fixed),
            // k = cb*16 + g*4 + r  (4 consecutive k's)
            short8 bk0 = frag(Ks, cb * 16 + qr, g);
            short8 bk1 = frag(Ks, cb * 16 + qr, 4 + g);
            f32x4 s = {};
            s = MFMA(bk0, aq0, s);
            s = MFMA(bk1, aq1, s);
            float p4[4];
#pragma unroll
            for (int r = 0; r < 4; r++) p4[r] = fexp2(s[r] * CE);
            if (kt == 16) {                        // mask pad keys (>= Lv)
                bool keep0 = (cb == 0) && (g == 0);   // only key 1024 valid
                p4[0] = keep0 ? p4[0] : 0.f;
                p4[1] = 0.f; p4[2] = 0.f; p4[3] = 0.f;
            }
            uint2 pw;
            pw.x = pk2(p4[0], p4[1]);
            pw.y = pk2(p4[2], p4[3]);
            // logical cols cb*16+4g..+3 -> chunk 2cb+(g>>1), half (g&1);
            // physical chunk = logical ^ q7 (row swizzle)
            *(uint2*)(prow + (((2 * cb + (g >> 1)) ^ q7) << 3) + ((g & 1) << 2)) = pw;
        }
        // own-row reads (same 4 lanes wrote this row); compiler inserts lgkm waits
        short8 ap0 = *(const short8*)(prow + ((g ^ q7) << 3));
        short8 ap1 = *(const short8*)(prow + (((4 + g) ^ q7) << 3));
        __builtin_amdgcn_s_setprio(1);
        sacc = MFMA(ap0, ones, sacc);              // exact row-sums of rounded P
        sacc = MFMA(ap1, ones, sacc);
#pragma unroll
        for (int cb = 0; cb < 4; cb++) {
            short8 bv0 = frag(Vs, cb * 16 + qr, g);
            short8 bv1 = frag(Vs, cb * 16 + qr, 4 + g);
            o[cb] = MFMA(ap0, bv0, o[cb]);
            o[cb] = MFMA(ap1, bv1, o[cb]);
        }
        __builtin_amdgcn_s_setprio(0);
        asm volatile("s_barrier" ::: "memory");    // reads of buf[kt&1] done
    }
    const int b = bh >> 4, h = bh & 15;
#pragma unroll
    for (int r = 0; r < 4; r++) {
        int lq = q0 + w * 16 + g * 4 + r;
        if (lq >= Lv) continue;
        float inv = 1.f / sacc[r];
        size_t ob = ((size_t)(b * 1025 + lq)) * 1024 + h * 64;
#pragma unroll
        for (int cb = 0; cb < 4; cb++)
            AO[ob + cb * 16 + qr] = f2b(o[cb][r] * inv);
    }
}

// ---------------- Proj GEMM + bias, fp32 out --------------------------------
__global__ __launch_bounds__(256, 4) void gemm_proj(const ushort_t* __restrict__ A,
                                                    const ushort_t* __restrict__ W,
                                                    const float* __restrict__ bias,
                                                    float* __restrict__ out) {
    __shared__ uint4 sm[2112];                     // 33792 B
    ushort_t* As = (ushort_t*)sm;
    ushort_t* Bs = As + 128 * 64;
    const int t = threadIdx.x;
    const int w = t >> 6, l = t & 63;
    const int m0 = blockIdx.y * 128, n0 = blockIdx.x * 128;
    const int wm = (w >> 1) * 64, wn = (w & 1) * 64;
    const int srow = (w * 32) + (l >> 3);
    const int scs = (l & 7) ^ (srow & 7);
    f32x4 acc[4][4] = {};
    for (int k0 = 0; k0 < 1024; k0 += 64) {
        __syncthreads();
#pragma unroll
        for (int i = 0; i < 4; i++) {
            int row = srow + i * 8;
            gl2lds16(A + (size_t)(m0 + row) * 1024 + k0 + scs * 8,
                     As + (w * 32 + i * 8) * 64);
            gl2lds16(W + (size_t)(n0 + row) * 1024 + k0 + scs * 8,
                     Bs + (w * 32 + i * 8) * 64);
        }
        __syncthreads();
#pragma unroll
        for (int kb = 0; kb < 2; kb++) {
            short8 af[4], bf[4];
#pragma unroll
            for (int mb = 0; mb < 4; mb++)
                af[mb] = frag(As, wm + mb * 16 + (l & 15), kb * 4 + (l >> 4));
#pragma unroll
            for (int nb = 0; nb < 4; nb++)
                bf[nb] = frag(Bs, wn + nb * 16 + (l & 15), kb * 4 + (l >> 4));
#pragma unroll
            for (int mb = 0; mb < 4; mb++)
#pragma unroll
                for (int nb = 0; nb < 4; nb++)
                    acc[mb][nb] = MFMA(af[mb], bf[nb], acc[mb][nb]);
        }
    }
    // ---- epilogue: stage fp32 in 64-row halves, store 512-B rows ----
    float bias4[4];
#pragma unroll
    for (int nb = 0; nb < 4; nb++) bias4[nb] = bias[n0 + wn + nb * 16 + (l & 15)];
    float (*Sf)[132] = (float(*)[132])sm;          // 64x132 fp32 = 33792 B
#pragma unroll
    for (int half = 0; half < 2; half++) {
        __syncthreads();
        if ((w >> 1) == half) {
#pragma unroll
            for (int mb = 0; mb < 4; mb++)
#pragma unroll
                for (int r = 0; r < 4; r++)
#pragma unroll
                    for (int nb = 0; nb < 4; nb++)
                        Sf[mb * 16 + (l >> 4) * 4 + r][wn + nb * 16 + (l & 15)] =
                            acc[mb][nb][r] + bias4[nb];
        }
        __syncthreads();
#pragma unroll
        for (int it = 0; it < 8; it++) {
            int rr = it * 8 + w * 2 + (l >> 5);
            int m = m0 + half * 64 + rr;
            if (m < Mv)
                *(float4*)(out + (size_t)m * 1024 + n0 + (l & 31) * 4) =
                    *(const float4*)&Sf[rr][(l & 31) * 4];
        }
    }
}

extern "C" void kernel_launch(void* const* d_in, const int* in_sizes, int n_in,
                              void* d_out, int out_size, void* d_ws, size_t ws_size,
                              hipStream_t stream) {
    (void)in_sizes; (void)n_in; (void)out_size; (void)ws_size;
    const float* x      = (const float*)d_in[0];
    const float* sinp   = (const float*)d_in[1];
    const float* cosp   = (const float*)d_in[2];
    const float* qkv_w  = (const float*)d_in[3];
    const float* proj_w = (const float*)d_in[4];
    const float* proj_b = (const float*)d_in[5];
    float* out = (float*)d_out;

    const size_t SZH = (size_t)BHv * LpD * 64;     // per Q/K/V tensor (bf16 elems)
    ushort_t* xb  = (ushort_t*)d_ws;               // [Mp][1024]
    ushort_t* qwb = xb + (size_t)Mp * 1024;        // [3072][1024]
    ushort_t* pwb = qwb + (size_t)3072 * 1024;     // [1024][1024]
    ushort_t* Qb  = pwb + (size_t)1024 * 1024;     // [BH][Lp][64]
    ushort_t* Kb  = Qb + SZH;
    ushort_t* Vb  = Kb + SZH;
    ushort_t* Vt  = Vb + SZH;                      // [BH][64][Lp]
    ushort_t* AO  = Vt + SZH;                      // [Mp][1024]

    dim3 blk(256);
    conv_bf16<<<dim3(Mp * 1024 / 1024), blk, 0, stream>>>(x, xb, Mv * 1024, Mp * 1024);
    conv_bf16<<<dim3(3072 * 1024 / 1024), blk, 0, stream>>>(qkv_w, qwb, 3072 * 1024, 3072 * 1024);
    conv_bf16<<<dim3(1024 * 1024 / 1024), blk, 0, stream>>>(proj_w, pwb, 1024 * 1024, 1024 * 1024);
    gemm_qkv<<<dim3(24, 129), blk, 0, stream>>>(xb, qwb, Qb, Kb, Vb, sinp, cosp);
    transpose_v<<<dim3(17, BHv), blk, 0, stream>>>(Vb, Vt);
    attn_mfma<<<dim3(17 * BHv), blk, 0, stream>>>(Qb, Kb, Vt, AO);
    gemm_proj<<<dim3(8, 129), blk, 0, stream>>>(AO, pwb, proj_b, out);
}

// Round 9
// 433.235 us; speedup vs baseline: 1.1996x; 1.0129x over previous
//
#include <hip/hip_runtime.h>

typedef unsigned short ushort_t;
typedef unsigned int uint_t;
typedef __attribute__((ext_vector_type(8))) short short8;
typedef __attribute__((ext_vector_type(4))) float f32x4;

#define Bv 16
#define Lv 1025
#define LpD 1088          // 17*64 padded sequence (K/V)
#define LpQ 1152          // 9*128 padded sequence (Q only)
#define Cv 1024
#define Hv 16
#define BHv 256
#define Mv 16400          // valid rows
#define Mp 16512          // 129*128 padded rows

#define MFMA(a, b, c) __builtin_amdgcn_mfma_f32_16x16x32_bf16(a, b, c, 0, 0, 0)

// f32 -> bf16 RNE via HW pack op (1 VALU op; identical RNE to software path)
__device__ __forceinline__ ushort_t f2b(float x) {
    uint_t r;
    asm("v_cvt_pk_bf16_f32 %0, %1, %1" : "=v"(r) : "v"(x));
    return (ushort_t)r;
}
__device__ __forceinline__ float b2f(ushort_t v) {
    return __uint_as_float(((uint_t)v) << 16);
}
// packed f32x2 -> bf16x2 (1 VALU op; no builtin on gfx950 -> inline asm)
__device__ __forceinline__ uint_t pk2(float a, float b) {
    uint_t r;
    asm("v_cvt_pk_bf16_f32 %0, %1, %2" : "=v"(r) : "v"(a), "v"(b));
    return r;
}
// raw 2^x (1 trans op; valid for the normal range our scores occupy)
__device__ __forceinline__ float fexp2(float x) {
    float r;
    asm("v_exp_f32 %0, %1" : "=v"(r) : "v"(x));
    return r;
}

// async global->LDS DMA, 16 B per lane; LDS dest = wave-uniform base + 16*lane
__device__ __forceinline__ void gl2lds16(const ushort_t* g, void* lds) {
    __builtin_amdgcn_global_load_lds(
        (const __attribute__((address_space(1))) void*)g,
        (__attribute__((address_space(3))) void*)lds, 16, 0, 0);
}

// XOR-swizzled frag read from an unpadded [rows][64] bf16 LDS tile:
// physical 16-B chunk p holds logical chunk p ^ (row & 7).
__device__ __forceinline__ short8 frag(const ushort_t* base, int row, int chunk) {
    return *(const short8*)(base + row * 64 + ((chunk ^ (row & 7)) << 3));
}

// ---------------- fp32 -> bf16 convert (pads tail with zeros) ---------------
__global__ __launch_bounds__(256) void conv_bf16(const float* __restrict__ s,
                                                 ushort_t* __restrict__ d,
                                                 int n_valid, int n_total) {
    int i = (blockIdx.x * 256 + threadIdx.x) * 4;
    if (i >= n_total) return;
    float4 v = make_float4(0.f, 0.f, 0.f, 0.f);
    if (i < n_valid) v = *(const float4*)(s + i);   // n_valid multiple of 4
    uint2 o;
    o.x = pk2(v.x, v.y);
    o.y = pk2(v.z, v.w);
    *(uint2*)(d + i) = o;
}

// ---------------- zero Q pad rows (Lv..LpQ-1 per bh) ------------------------
// attn tile 8 stages Q rows 1024..1151; rows 1025+ are never written by the
// GEMM. Zero them so exp2 sees finite scores (outputs masked at store anyway).
// 256 bh * 127 rows * 64 elems / 8 per thread = 260096 threads = 1016 blocks.
__global__ __launch_bounds__(256) void zero_qpad(ushort_t* __restrict__ Qb) {
    int e8 = (blockIdx.x * 256 + threadIdx.x) * 8;
    int bh = e8 / 8128;                 // 127*64
    int rem = e8 - bh * 8128;
    *(uint4*)(Qb + (size_t)bh * LpQ * 64 + (size_t)Lv * 64 + rem) =
        make_uint4(0u, 0u, 0u, 0u);
}

// ---------------- QKV GEMM: C[m][n] = sum_k A[m][k] W[n][k] -----------------
// RoPE fused into the epilogue (reads the full 64-dim head row from St; the
// rotate-half partner of dim d is d^32 in the same row).
__global__ __launch_bounds__(256, 4) void gemm_qkv(const ushort_t* __restrict__ A,
                                                   const ushort_t* __restrict__ W,
                                                   ushort_t* __restrict__ Q,
                                                   ushort_t* __restrict__ K,
                                                   ushort_t* __restrict__ V,
                                                   const float* __restrict__ sinp,
                                                   const float* __restrict__ cosp) {
    __shared__ uint4 sm[2112];                     // 33792 B
    ushort_t* As = (ushort_t*)sm;                  // [128][64] swizzled
    ushort_t* Bs = As + 128 * 64;                  // [128][64] swizzled
    const int t = threadIdx.x;
    const int w = t >> 6, l = t & 63;
    const int m0 = blockIdx.y * 128, n0 = blockIdx.x * 128;
    const int wm = (w >> 1) * 64, wn = (w & 1) * 64;
    const int srow = (w * 32) + (l >> 3);          // staging row base for i=0
    const int scs = (l & 7) ^ (srow & 7);          // swizzled chunk
    f32x4 acc[4][4] = {};
    for (int k0 = 0; k0 < 1024; k0 += 64) {
        __syncthreads();                           // prev frag reads done
#pragma unroll
        for (int i = 0; i < 4; i++) {
            int row = srow + i * 8;
            gl2lds16(A + (size_t)(m0 + row) * 1024 + k0 + scs * 8,
                     As + (w * 32 + i * 8) * 64);
            gl2lds16(W + (size_t)(n0 + row) * 1024 + k0 + scs * 8,
                     Bs + (w * 32 + i * 8) * 64);
        }
        __syncthreads();                           // drains vmcnt(0): LDS valid
#pragma unroll
        for (int kb = 0; kb < 2; kb++) {
            short8 af[4], bf[4];
#pragma unroll
            for (int mb = 0; mb < 4; mb++)
                af[mb] = frag(As, wm + mb * 16 + (l & 15), kb * 4 + (l >> 4));
#pragma unroll
            for (int nb = 0; nb < 4; nb++)
                bf[nb] = frag(Bs, wn + nb * 16 + (l & 15), kb * 4 + (l >> 4));
#pragma unroll
            for (int mb = 0; mb < 4; mb++)
#pragma unroll
                for (int nb = 0; nb < 4; nb++)
                    acc[mb][nb] = MFMA(af[mb], bf[nb], acc[mb][nb]);
        }
    }
    // ---- epilogue: LDS-staged, coalesced 128-B stores, fused RoPE ----
    __syncthreads();
    ushort_t (*St)[132] = (ushort_t(*)[132])sm;    // 128x132 bf16 = 33792 B
#pragma unroll
    for (int mb = 0; mb < 4; mb++)
#pragma unroll
        for (int r = 0; r < 4; r++)
#pragma unroll
            for (int nb = 0; nb < 4; nb++)
                St[wm + mb * 16 + (l >> 4) * 4 + r][wn + nb * 16 + (l & 15)] =
                    f2b(acc[mb][nb][r]);
    __syncthreads();
#pragma unroll
    for (int it = 0; it < 8; it++) {
        int seg = it * 32 + w * 8 + (l >> 3);
        int mr = seg >> 1, p = seg & 1;
        int m = m0 + mr;
        if (m >= Mv) continue;
        int b = m / 1025, lseq = m - b * 1025;
        int n = n0 + p * 64;
        int which = n >> 10, h = (n >> 6) & 15;
        ushort_t* dst = (which == 0) ? Q : ((which == 1) ? K : V);
        const size_t stride = (which == 0) ? (size_t)LpQ : (size_t)LpD;
        const int d0 = (l & 7) * 8;
        size_t doff = ((size_t)(b * Hv + h) * stride + lseq) * 64 + d0;
        if (which <= 1 && lseq > 0) {
            // RoPE on patch rows of Q and K
            const ushort_t* rowp = &St[mr][p * 64];
            const float* cw = cosp + (lseq - 1) * 64 + d0;
            const float* sw = sinp + (lseq - 1) * 64 + d0;
            float4 c0 = *(const float4*)cw, c1 = *(const float4*)(cw + 4);
            float4 s0 = *(const float4*)sw, s1 = *(const float4*)(sw + 4);
            float cc[8] = {c0.x, c0.y, c0.z, c0.w, c1.x, c1.y, c1.z, c1.w};
            float ss[8] = {s0.x, s0.y, s0.z, s0.w, s1.x, s1.y, s1.z, s1.w};
            float sgn = (d0 < 32) ? -1.f : 1.f;    // rot = [-t2, t1]
            uint_t ov[4];
#pragma unroll
            for (int jj = 0; jj < 4; jj++) {
                float f0 = b2f(rowp[d0 + jj * 2]);
                float f1 = b2f(rowp[d0 + jj * 2 + 1]);
                float r0 = b2f(rowp[(d0 ^ 32) + jj * 2]) * sgn;
                float r1 = b2f(rowp[(d0 ^ 32) + jj * 2 + 1]) * sgn;
                ov[jj] = pk2(f0 * cc[jj * 2] + r0 * ss[jj * 2],
                             f1 * cc[jj * 2 + 1] + r1 * ss[jj * 2 + 1]);
            }
            *(uint4*)(dst + doff) = *(uint4*)ov;
        } else {
            *(uint4*)(dst + doff) = *(const uint4*)&St[mr][p * 64 + d0];
        }
    }
}

// ---------------- V transpose: [BH][Lp][64] -> [BH][64][Lp] -----------------
// Source rows >= Lv are never written by gemm_qkv (stale workspace). They are
// multiplied by P==0 in attn's last tile; 0*Inf/NaN = NaN would contaminate
// valid rows, so substitute exact zeros here (content-independent safety).
__global__ __launch_bounds__(256) void transpose_v(const ushort_t* __restrict__ Vb,
                                                   ushort_t* __restrict__ Vt) {
    __shared__ ushort_t Ts[64][72];
    const int t = threadIdx.x;
    const int l0 = blockIdx.x * 64, bh = blockIdx.y;
#pragma unroll
    for (int i = 0; i < 2; i++) {
        int c = t + 256 * i; int row = c >> 3, cir = c & 7;
        uint4 v = make_uint4(0u, 0u, 0u, 0u);
        if (l0 + row < Lv)
            v = *(const uint4*)(Vb + ((size_t)bh * LpD + l0 + row) * 64 + cir * 8);
        *(uint4*)&Ts[row][cir * 8] = v;
    }
    __syncthreads();
#pragma unroll
    for (int i = 0; i < 2; i++) {
        int c = t + 256 * i; int d = c >> 3, lg = c & 7;
        short8 v;
#pragma unroll
        for (int j = 0; j < 8; j++) v[j] = (short)Ts[lg * 8 + j][d];
        *(short8*)(Vt + ((size_t)bh * 64 + d) * LpD + l0 + lg * 8) = v;
    }
}

// ---------------- Attention: block = (q-tile 128, bh), 8 waves. -------------
// Per-wave code identical to the verified 4-wave version (each wave owns 16
// q-rows); 8 waves share each K/V tile -> staging DMA per q-row halves and
// occupancy rises to 24 waves/CU (3 blocks x 8). Swapped QK^T; P overlays the
// dead Q tile; double-buffered K/V DMA with counted vmcnt; XCD swizzle.
__global__ __launch_bounds__(512, 6) void attn_mfma(const ushort_t* __restrict__ Qb,
                                                    const ushort_t* __restrict__ Kb,
                                                    const ushort_t* __restrict__ Vt,
                                                    ushort_t* __restrict__ AO) {
    __shared__ ushort_t QP[128 * 64];              // Q tile, then P tile (overlay)
    __shared__ ushort_t Kd[2][64 * 64];            // double-buffered, swizzled
    __shared__ ushort_t Vd[2][64 * 64];
    const int t = threadIdx.x, w = t >> 6, l = t & 63;
    const int wg = blockIdx.x;                     // 0..2303, 1-D grid
    const int nid = (wg & 7) * 288 + (wg >> 3);    // bijective XCD swizzle (8*288)
    const int bh = nid / 9, qt = nid - bh * 9;
    const int q0 = qt * 128;
    const size_t qbase = (size_t)bh * LpQ * 64;
    const size_t kbase = (size_t)bh * LpD * 64;
    const size_t vbase = (size_t)bh * 64 * LpD;
    const int scs = (l & 7) ^ ((l >> 3) & 7);      // swizzled chunk for staging
    const int g = l >> 4;                          // 0..3 lane group
    const int qr = l & 15;                         // q-row / d-col within tile
    const int q7 = l & 7;                          // row-swizzle key for P

#pragma unroll
    for (int i = 0; i < 2; i++) {                  // Q: wave w stages 16 rows
        int row = w * 16 + i * 8 + (l >> 3);
        gl2lds16(Qb + qbase + (size_t)(q0 + row) * 64 + scs * 8,
                 QP + (w * 16 + i * 8) * 64);
    }
    {                                              // K/V tile 0: 8 rows per wave
        int row = w * 8 + (l >> 3);
        gl2lds16(Kb + kbase + (size_t)row * 64 + scs * 8, Kd[0] + (w * 8) * 64);
        gl2lds16(Vt + vbase + (size_t)row * LpD + scs * 8, Vd[0] + (w * 8) * 64);
    }
    asm volatile("s_waitcnt vmcnt(2)" ::: "memory");   // Q resident (tile0 may fly)
    asm volatile("s_barrier" ::: "memory");
    short8 aq0 = frag(QP, w * 16 + qr, g);
    short8 aq1 = frag(QP, w * 16 + qr, 4 + g);
    // Drain own ds_reads of QP BEFORE the kt=0 barrier: after that barrier
    // other waves overwrite QP with P values (overlay).
    asm volatile("s_waitcnt lgkmcnt(0)" ::: "memory");

    ushort_t* prow = QP + (w * 16 + qr) * 64;      // this lane's P row

    short8 ones;
#pragma unroll
    for (int j = 0; j < 8; j++) ones[j] = (short)0x3F80;   // 1.0 bf16
    f32x4 o[4] = {};
    f32x4 sacc = {};
    const float CE = 0.18033688011112042f;  // log2(e)/8: exp(s/8) = exp2(s*CE)

    for (int kt = 0; kt < 17; kt++) {
        const ushort_t* Ks = Kd[kt & 1];
        const ushort_t* Vs = Vd[kt & 1];
        if (kt < 16) {                             // prefetch tile kt+1
            int row = w * 8 + (l >> 3);
            gl2lds16(Kb + kbase + (size_t)((kt + 1) * 64 + row) * 64 + scs * 8,
                     Kd[(kt + 1) & 1] + (w * 8) * 64);
            gl2lds16(Vt + vbase + (size_t)row * LpD + (kt + 1) * 64 + scs * 8,
                     Vd[(kt + 1) & 1] + (w * 8) * 64);
            asm volatile("s_waitcnt vmcnt(2)" ::: "memory");  // tile kt landed
        } else {
            asm volatile("s_waitcnt vmcnt(0)" ::: "memory");  // last tile
        }
        asm volatile("s_barrier" ::: "memory");    // all waves: tile kt valid
#pragma unroll
        for (int cb = 0; cb < 4; cb++) {
            // swapped operands: D[k][q]; this lane: q = w*16+qr (fixed),
            // k = cb*16 + g*4 + r  (4 consecutive k's)
            short8 bk0 = frag(Ks, cb * 16 + qr, g);
            short8 bk1 = frag(Ks, cb * 16 + qr, 4 + g);
            f32x4 s = {};
            s = MFMA(bk0, aq0, s);
            s = MFMA(bk1, aq1, s);
            float p4[4];
#pragma unroll
            for (int r = 0; r < 4; r++) p4[r] = fexp2(s[r] * CE);
            if (kt == 16) {                        // mask pad keys (>= Lv)
                bool keep0 = (cb == 0) && (g == 0);   // only key 1024 valid
                p4[0] = keep0 ? p4[0] : 0.f;
                p4[1] = 0.f; p4[2] = 0.f; p4[3] = 0.f;
            }
            uint2 pw;
            pw.x = pk2(p4[0], p4[1]);
            pw.y = pk2(p4[2], p4[3]);
            // logical cols cb*16+4g..+3 -> chunk 2cb+(g>>1), half (g&1);
            // physical chunk = logical ^ q7 (row swizzle)
            *(uint2*)(prow + (((2 * cb + (g >> 1)) ^ q7) << 3) + ((g & 1) << 2)) = pw;
        }
        // own-row reads (same 4 lanes wrote this row); compiler inserts lgkm waits
        short8 ap0 = *(const short8*)(prow + ((g ^ q7) << 3));
        short8 ap1 = *(const short8*)(prow + (((4 + g) ^ q7) << 3));
        __builtin_amdgcn_s_setprio(1);
        sacc = MFMA(ap0, ones, sacc);              // exact row-sums of rounded P
        sacc = MFMA(ap1, ones, sacc);
#pragma unroll
        for (int cb = 0; cb < 4; cb++) {
            short8 bv0 = frag(Vs, cb * 16 + qr, g);
            short8 bv1 = frag(Vs, cb * 16 + qr, 4 + g);
            o[cb] = MFMA(ap0, bv0, o[cb]);
            o[cb] = MFMA(ap1, bv1, o[cb]);
        }
        __builtin_amdgcn_s_setprio(0);
        asm volatile("s_barrier" ::: "memory");    // reads of buf[kt&1] done
    }
    const int b = bh >> 4, h = bh & 15;
#pragma unroll
    for (int r = 0; r < 4; r++) {
        int lq = q0 + w * 16 + g * 4 + r;
        if (lq >= Lv) continue;
        float inv = 1.f / sacc[r];
        size_t ob = ((size_t)(b * 1025 + lq)) * 1024 + h * 64;
#pragma unroll
        for (int cb = 0; cb < 4; cb++)
            AO[ob + cb * 16 + qr] = f2b(o[cb][r] * inv);
    }
}

// ---------------- Proj GEMM + bias, fp32 out --------------------------------
__global__ __launch_bounds__(256, 4) void gemm_proj(const ushort_t* __restrict__ A,
                                                    const ushort_t* __restrict__ W,
                                                    const float* __restrict__ bias,
                                                    float* __restrict__ out) {
    __shared__ uint4 sm[2112];                     // 33792 B
    ushort_t* As = (ushort_t*)sm;
    ushort_t* Bs = As + 128 * 64;
    const int t = threadIdx.x;
    const int w = t >> 6, l = t & 63;
    const int m0 = blockIdx.y * 128, n0 = blockIdx.x * 128;
    const int wm = (w >> 1) * 64, wn = (w & 1) * 64;
    const int srow = (w * 32) + (l >> 3);
    const int scs = (l & 7) ^ (srow & 7);
    f32x4 acc[4][4] = {};
    for (int k0 = 0; k0 < 1024; k0 += 64) {
        __syncthreads();
#pragma unroll
        for (int i = 0; i < 4; i++) {
            int row = srow + i * 8;
            gl2lds16(A + (size_t)(m0 + row) * 1024 + k0 + scs * 8,
                     As + (w * 32 + i * 8) * 64);
            gl2lds16(W + (size_t)(n0 + row) * 1024 + k0 + scs * 8,
                     Bs + (w * 32 + i * 8) * 64);
        }
        __syncthreads();
#pragma unroll
        for (int kb = 0; kb < 2; kb++) {
            short8 af[4], bf[4];
#pragma unroll
            for (int mb = 0; mb < 4; mb++)
                af[mb] = frag(As, wm + mb * 16 + (l & 15), kb * 4 + (l >> 4));
#pragma unroll
            for (int nb = 0; nb < 4; nb++)
                bf[nb] = frag(Bs, wn + nb * 16 + (l & 15), kb * 4 + (l >> 4));
#pragma unroll
            for (int mb = 0; mb < 4; mb++)
#pragma unroll
                for (int nb = 0; nb < 4; nb++)
                    acc[mb][nb] = MFMA(af[mb], bf[nb], acc[mb][nb]);
        }
    }
    // ---- epilogue: stage fp32 in 64-row halves, store 512-B rows ----
    float bias4[4];
#pragma unroll
    for (int nb = 0; nb < 4; nb++) bias4[nb] = bias[n0 + wn + nb * 16 + (l & 15)];
    float (*Sf)[132] = (float(*)[132])sm;          // 64x132 fp32 = 33792 B
#pragma unroll
    for (int half = 0; half < 2; half++) {
        __syncthreads();
        if ((w >> 1) == half) {
#pragma unroll
            for (int mb = 0; mb < 4; mb++)
#pragma unroll
                for (int r = 0; r < 4; r++)
#pragma unroll
                    for (int nb = 0; nb < 4; nb++)
                        Sf[mb * 16 + (l >> 4) * 4 + r][wn + nb * 16 + (l & 15)] =
                            acc[mb][nb][r] + bias4[nb];
        }
        __syncthreads();
#pragma unroll
        for (int it = 0; it < 8; it++) {
            int rr = it * 8 + w * 2 + (l >> 5);
            int m = m0 + half * 64 + rr;
            if (m < Mv)
                *(float4*)(out + (size_t)m * 1024 + n0 + (l & 31) * 4) =
                    *(const float4*)&Sf[rr][(l & 31) * 4];
        }
    }
}

extern "C" void kernel_launch(void* const* d_in, const int* in_sizes, int n_in,
                              void* d_out, int out_size, void* d_ws, size_t ws_size,
                              hipStream_t stream) {
    (void)in_sizes; (void)n_in; (void)out_size; (void)ws_size;
    const float* x      = (const float*)d_in[0];
    const float* sinp   = (const float*)d_in[1];
    const float* cosp   = (const float*)d_in[2];
    const float* qkv_w  = (const float*)d_in[3];
    const float* proj_w = (const float*)d_in[4];
    const float* proj_b = (const float*)d_in[5];
    float* out = (float*)d_out;

    const size_t SZQ = (size_t)BHv * LpQ * 64;     // Q tensor (bf16 elems)
    const size_t SZH = (size_t)BHv * LpD * 64;     // per K/V tensor (bf16 elems)
    ushort_t* xb  = (ushort_t*)d_ws;               // [Mp][1024]
    ushort_t* qwb = xb + (size_t)Mp * 1024;        // [3072][1024]
    ushort_t* pwb = qwb + (size_t)3072 * 1024;     // [1024][1024]
    ushort_t* Qb  = pwb + (size_t)1024 * 1024;     // [BH][LpQ][64]
    ushort_t* Kb  = Qb + SZQ;                      // [BH][LpD][64]
    ushort_t* Vb  = Kb + SZH;
    ushort_t* Vt  = Vb + SZH;                      // [BH][64][LpD]
    ushort_t* AO  = xb;                            // alias: xb dead after gemm_qkv;
                                                   // in-order stream, conv rewrites xb

    dim3 blk(256);
    conv_bf16<<<dim3(Mp * 1024 / 1024), blk, 0, stream>>>(x, xb, Mv * 1024, Mp * 1024);
    conv_bf16<<<dim3(3072 * 1024 / 1024), blk, 0, stream>>>(qkv_w, qwb, 3072 * 1024, 3072 * 1024);
    conv_bf16<<<dim3(1024 * 1024 / 1024), blk, 0, stream>>>(proj_w, pwb, 1024 * 1024, 1024 * 1024);
    zero_qpad<<<dim3(1016), blk, 0, stream>>>(Qb);
    gemm_qkv<<<dim3(24, 129), blk, 0, stream>>>(xb, qwb, Qb, Kb, Vb, sinp, cosp);
    transpose_v<<<dim3(17, BHv), blk, 0, stream>>>(Vb, Vt);
    attn_mfma<<<dim3(9 * BHv), dim3(512), 0, stream>>>(Qb, Kb, Vt, AO);
    gemm_proj<<<dim3(8, 129), blk, 0, stream>>>(AO, pwb, proj_b, out);
}

// Round 11
// 407.962 us; speedup vs baseline: 1.2740x; 1.0620x over previous
//
#include <hip/hip_runtime.h>

typedef unsigned short ushort_t;
typedef unsigned int uint_t;
typedef __attribute__((ext_vector_type(8))) short short8;
typedef __attribute__((ext_vector_type(4))) float f32x4;

#define Bv 16
#define Lv 1025
#define LpD 1088          // 17*64 padded sequence (K/V)
#define LpQ 1152          // 9*128 padded sequence (Q only)
#define Cv 1024
#define Hv 16
#define BHv 256
#define Mv 16400          // valid rows
#define Mp 16512          // 129*128 padded rows

#define MFMA(a, b, c) __builtin_amdgcn_mfma_f32_16x16x32_bf16(a, b, c, 0, 0, 0)

// f32 -> bf16 RNE via HW pack op (1 VALU op; identical RNE to software path)
__device__ __forceinline__ ushort_t f2b(float x) {
    uint_t r;
    asm("v_cvt_pk_bf16_f32 %0, %1, %1" : "=v"(r) : "v"(x));
    return (ushort_t)r;
}
__device__ __forceinline__ float b2f(ushort_t v) {
    return __uint_as_float(((uint_t)v) << 16);
}
// packed f32x2 -> bf16x2 (1 VALU op; no builtin on gfx950 -> inline asm)
__device__ __forceinline__ uint_t pk2(float a, float b) {
    uint_t r;
    asm("v_cvt_pk_bf16_f32 %0, %1, %2" : "=v"(r) : "v"(a), "v"(b));
    return r;
}
// raw 2^x (1 trans op; valid for the normal range our scores occupy)
__device__ __forceinline__ float fexp2(float x) {
    float r;
    asm("v_exp_f32 %0, %1" : "=v"(r) : "v"(x));
    return r;
}

// async global->LDS DMA, 16 B per lane; LDS dest = wave-uniform base + 16*lane
__device__ __forceinline__ void gl2lds16(const ushort_t* g, void* lds) {
    __builtin_amdgcn_global_load_lds(
        (const __attribute__((address_space(1))) void*)g,
        (__attribute__((address_space(3))) void*)lds, 16, 0, 0);
}

// XOR-swizzled frag read from an unpadded [rows][64] bf16 LDS tile:
// physical 16-B chunk p holds logical chunk p ^ (row & 7).
__device__ __forceinline__ short8 frag(const ushort_t* base, int row, int chunk) {
    return *(const short8*)(base + row * 64 + ((chunk ^ (row & 7)) << 3));
}

// ---------------- fp32 -> bf16 convert (pads tail with zeros) ---------------
__global__ __launch_bounds__(256) void conv_bf16(const float* __restrict__ s,
                                                 ushort_t* __restrict__ d,
                                                 int n_valid, int n_total) {
    int i = (blockIdx.x * 256 + threadIdx.x) * 4;
    if (i >= n_total) return;
    float4 v = make_float4(0.f, 0.f, 0.f, 0.f);
    if (i < n_valid) v = *(const float4*)(s + i);   // n_valid multiple of 4
    uint2 o;
    o.x = pk2(v.x, v.y);
    o.y = pk2(v.z, v.w);
    *(uint2*)(d + i) = o;
}

// ---------------- zero Q pad rows (Lv..LpQ-1 per bh) ------------------------
// attn tile 8 stages Q rows 1024..1151; rows 1025+ are never written by the
// GEMM. Zero them so exp2 sees finite scores (outputs masked at store anyway).
__global__ __launch_bounds__(256) void zero_qpad(ushort_t* __restrict__ Qb) {
    int e8 = (blockIdx.x * 256 + threadIdx.x) * 8;
    int bh = e8 / 8128;                 // 127*64
    int rem = e8 - bh * 8128;
    *(uint4*)(Qb + (size_t)bh * LpQ * 64 + (size_t)Lv * 64 + rem) =
        make_uint4(0u, 0u, 0u, 0u);
}

// ---------------- QKV GEMM: C[m][n] = sum_k A[m][k] W[n][k] -----------------
// RoPE fused into the epilogue. 1-D grid, bijective XCD swizzle (3096=8*387):
// each XCD owns contiguous nid range -> A-panel reuse lands in one L2.
__global__ __launch_bounds__(256, 4) void gemm_qkv(const ushort_t* __restrict__ A,
                                                   const ushort_t* __restrict__ W,
                                                   ushort_t* __restrict__ Q,
                                                   ushort_t* __restrict__ K,
                                                   ushort_t* __restrict__ V,
                                                   const float* __restrict__ sinp,
                                                   const float* __restrict__ cosp) {
    __shared__ uint4 sm[2112];                     // 33792 B
    ushort_t* As = (ushort_t*)sm;                  // [128][64] swizzled
    ushort_t* Bs = As + 128 * 64;                  // [128][64] swizzled
    const int t = threadIdx.x;
    const int w = t >> 6, l = t & 63;
    const int wg = blockIdx.x;
    const int nid = (wg & 7) * 387 + (wg >> 3);    // XCD swizzle, bijective
    const int mb0 = nid / 24;
    const int m0 = mb0 * 128, n0 = (nid - mb0 * 24) * 128;
    const int wm = (w >> 1) * 64, wn = (w & 1) * 64;
    const int srow = (w * 32) + (l >> 3);          // staging row base for i=0
    const int scs = (l & 7) ^ (srow & 7);          // swizzled chunk
    f32x4 acc[4][4] = {};
    for (int k0 = 0; k0 < 1024; k0 += 64) {
        __syncthreads();                           // prev frag reads done
#pragma unroll
        for (int i = 0; i < 4; i++) {
            int row = srow + i * 8;
            gl2lds16(A + (size_t)(m0 + row) * 1024 + k0 + scs * 8,
                     As + (w * 32 + i * 8) * 64);
            gl2lds16(W + (size_t)(n0 + row) * 1024 + k0 + scs * 8,
                     Bs + (w * 32 + i * 8) * 64);
        }
        __syncthreads();                           // drains vmcnt(0): LDS valid
#pragma unroll
        for (int kb = 0; kb < 2; kb++) {
            short8 af[4], bf[4];
#pragma unroll
            for (int mb = 0; mb < 4; mb++)
                af[mb] = frag(As, wm + mb * 16 + (l & 15), kb * 4 + (l >> 4));
#pragma unroll
            for (int nb = 0; nb < 4; nb++)
                bf[nb] = frag(Bs, wn + nb * 16 + (l & 15), kb * 4 + (l >> 4));
#pragma unroll
            for (int mb = 0; mb < 4; mb++)
#pragma unroll
                for (int nb = 0; nb < 4; nb++)
                    acc[mb][nb] = MFMA(af[mb], bf[nb], acc[mb][nb]);
        }
    }
    // ---- epilogue: LDS-staged, coalesced 128-B stores, fused RoPE ----
    __syncthreads();
    ushort_t (*St)[132] = (ushort_t(*)[132])sm;    // 128x132 bf16 = 33792 B
#pragma unroll
    for (int mb = 0; mb < 4; mb++)
#pragma unroll
        for (int r = 0; r < 4; r++)
#pragma unroll
            for (int nb = 0; nb < 4; nb++)
                St[wm + mb * 16 + (l >> 4) * 4 + r][wn + nb * 16 + (l & 15)] =
                    f2b(acc[mb][nb][r]);
    __syncthreads();
#pragma unroll
    for (int it = 0; it < 8; it++) {
        int seg = it * 32 + w * 8 + (l >> 3);
        int mr = seg >> 1, p = seg & 1;
        int m = m0 + mr;
        if (m >= Mv) continue;
        int b = m / 1025, lseq = m - b * 1025;
        int n = n0 + p * 64;
        int which = n >> 10, h = (n >> 6) & 15;
        ushort_t* dst = (which == 0) ? Q : ((which == 1) ? K : V);
        const size_t stride = (which == 0) ? (size_t)LpQ : (size_t)LpD;
        const int d0 = (l & 7) * 8;
        size_t doff = ((size_t)(b * Hv + h) * stride + lseq) * 64 + d0;
        if (which <= 1 && lseq > 0) {
            // RoPE on patch rows of Q and K
            const ushort_t* rowp = &St[mr][p * 64];
            const float* cw = cosp + (lseq - 1) * 64 + d0;
            const float* sw = sinp + (lseq - 1) * 64 + d0;
            float4 c0 = *(const float4*)cw, c1 = *(const float4*)(cw + 4);
            float4 s0 = *(const float4*)sw, s1 = *(const float4*)(sw + 4);
            float cc[8] = {c0.x, c0.y, c0.z, c0.w, c1.x, c1.y, c1.z, c1.w};
            float ss[8] = {s0.x, s0.y, s0.z, s0.w, s1.x, s1.y, s1.z, s1.w};
            float sgn = (d0 < 32) ? -1.f : 1.f;    // rot = [-t2, t1]
            uint_t ov[4];
#pragma unroll
            for (int jj = 0; jj < 4; jj++) {
                float f0 = b2f(rowp[d0 + jj * 2]);
                float f1 = b2f(rowp[d0 + jj * 2 + 1]);
                float r0 = b2f(rowp[(d0 ^ 32) + jj * 2]) * sgn;
                float r1 = b2f(rowp[(d0 ^ 32) + jj * 2 + 1]) * sgn;
                ov[jj] = pk2(f0 * cc[jj * 2] + r0 * ss[jj * 2],
                             f1 * cc[jj * 2 + 1] + r1 * ss[jj * 2 + 1]);
            }
            *(uint4*)(dst + doff) = *(uint4*)ov;
        } else {
            *(uint4*)(dst + doff) = *(const uint4*)&St[mr][p * 64 + d0];
        }
    }
}

// ---------------- V transpose: [BH][Lp][64] -> [BH][64][Lp] -----------------
// Source rows >= Lv are never written by gemm_qkv (stale workspace). They are
// multiplied by P==0 in attn's last tile; 0*Inf/NaN = NaN would contaminate
// valid rows, so substitute exact zeros here (content-independent safety).
__global__ __launch_bounds__(256) void transpose_v(const ushort_t* __restrict__ Vb,
                                                   ushort_t* __restrict__ Vt) {
    __shared__ ushort_t Ts[64][72];
    const int t = threadIdx.x;
    const int l0 = blockIdx.x * 64, bh = blockIdx.y;
#pragma unroll
    for (int i = 0; i < 2; i++) {
        int c = t + 256 * i; int row = c >> 3, cir = c & 7;
        uint4 v = make_uint4(0u, 0u, 0u, 0u);
        if (l0 + row < Lv)
            v = *(const uint4*)(Vb + ((size_t)bh * LpD + l0 + row) * 64 + cir * 8);
        *(uint4*)&Ts[row][cir * 8] = v;
    }
    __syncthreads();
#pragma unroll
    for (int i = 0; i < 2; i++) {
        int c = t + 256 * i; int d = c >> 3, lg = c & 7;
        short8 v;
#pragma unroll
        for (int j = 0; j < 8; j++) v[j] = (short)Ts[lg * 8 + j][d];
        *(short8*)(Vt + ((size_t)bh * 64 + d) * LpD + l0 + lg * 8) = v;
    }
}

// ---------------- Attention: block = (q-tile 128, bh), 8 waves. -------------
// Verified round-9 structure, unchanged. Swapped QK^T; P overlays the dead Q
// tile; double-buffered K/V DMA with counted vmcnt; XCD swizzle.
__global__ __launch_bounds__(512, 6) void attn_mfma(const ushort_t* __restrict__ Qb,
                                                    const ushort_t* __restrict__ Kb,
                                                    const ushort_t* __restrict__ Vt,
                                                    ushort_t* __restrict__ AO) {
    __shared__ ushort_t QP[128 * 64];              // Q tile, then P tile (overlay)
    __shared__ ushort_t Kd[2][64 * 64];            // double-buffered, swizzled
    __shared__ ushort_t Vd[2][64 * 64];
    const int t = threadIdx.x, w = t >> 6, l = t & 63;
    const int wg = blockIdx.x;                     // 0..2303, 1-D grid
    const int nid = (wg & 7) * 288 + (wg >> 3);    // bijective XCD swizzle (8*288)
    const int bh = nid / 9, qt = nid - bh * 9;
    const int q0 = qt * 128;
    const size_t qbase = (size_t)bh * LpQ * 64;
    const size_t kbase = (size_t)bh * LpD * 64;
    const size_t vbase = (size_t)bh * 64 * LpD;
    const int scs = (l & 7) ^ ((l >> 3) & 7);      // swizzled chunk for staging
    const int g = l >> 4;                          // 0..3 lane group
    const int qr = l & 15;                         // q-row / d-col within tile
    const int q7 = l & 7;                          // row-swizzle key for P

#pragma unroll
    for (int i = 0; i < 2; i++) {                  // Q: wave w stages 16 rows
        int row = w * 16 + i * 8 + (l >> 3);
        gl2lds16(Qb + qbase + (size_t)(q0 + row) * 64 + scs * 8,
                 QP + (w * 16 + i * 8) * 64);
    }
    {                                              // K/V tile 0: 8 rows per wave
        int row = w * 8 + (l >> 3);
        gl2lds16(Kb + kbase + (size_t)row * 64 + scs * 8, Kd[0] + (w * 8) * 64);
        gl2lds16(Vt + vbase + (size_t)row * LpD + scs * 8, Vd[0] + (w * 8) * 64);
    }
    asm volatile("s_waitcnt vmcnt(2)" ::: "memory");   // Q resident (tile0 may fly)
    asm volatile("s_barrier" ::: "memory");
    short8 aq0 = frag(QP, w * 16 + qr, g);
    short8 aq1 = frag(QP, w * 16 + qr, 4 + g);
    // Drain own ds_reads of QP BEFORE the kt=0 barrier: after that barrier
    // other waves overwrite QP with P values (overlay).
    asm volatile("s_waitcnt lgkmcnt(0)" ::: "memory");

    ushort_t* prow = QP + (w * 16 + qr) * 64;      // this lane's P row

    short8 ones;
#pragma unroll
    for (int j = 0; j < 8; j++) ones[j] = (short)0x3F80;   // 1.0 bf16
    f32x4 o[4] = {};
    f32x4 sacc = {};
    const float CE = 0.18033688011112042f;  // log2(e)/8: exp(s/8) = exp2(s*CE)

    for (int kt = 0; kt < 17; kt++) {
        const ushort_t* Ks = Kd[kt & 1];
        const ushort_t* Vs = Vd[kt & 1];
        if (kt < 16) {                             // prefetch tile kt+1
            int row = w * 8 + (l >> 3);
            gl2lds16(Kb + kbase + (size_t)((kt + 1) * 64 + row) * 64 + scs * 8,
                     Kd[(kt + 1) & 1] + (w * 8) * 64);
            gl2lds16(Vt + vbase + (size_t)row * LpD + (kt + 1) * 64 + scs * 8,
                     Vd[(kt + 1) & 1] + (w * 8) * 64);
            asm volatile("s_waitcnt vmcnt(2)" ::: "memory");  // tile kt landed
        } else {
            asm volatile("s_waitcnt vmcnt(0)" ::: "memory");  // last tile
        }
        asm volatile("s_barrier" ::: "memory");    // all waves: tile kt valid
#pragma unroll
        for (int cb = 0; cb < 4; cb++) {
            // swapped operands: D[k][q]; this lane: q = w*16+qr (fixed),
            // k = cb*16 + g*4 + r  (4 consecutive k's)
            short8 bk0 = frag(Ks, cb * 16 + qr, g);
            short8 bk1 = frag(Ks, cb * 16 + qr, 4 + g);
            f32x4 s = {};
            s = MFMA(bk0, aq0, s);
            s = MFMA(bk1, aq1, s);
            float p4[4];
#pragma unroll
            for (int r = 0; r < 4; r++) p4[r] = fexp2(s[r] * CE);
            if (kt == 16) {                        // mask pad keys (>= Lv)
                bool keep0 = (cb == 0) && (g == 0);   // only key 1024 valid
                p4[0] = keep0 ? p4[0] : 0.f;
                p4[1] = 0.f; p4[2] = 0.f; p4[3] = 0.f;
            }
            uint2 pw;
            pw.x = pk2(p4[0], p4[1]);
            pw.y = pk2(p4[2], p4[3]);
            // logical cols cb*16+4g..+3 -> chunk 2cb+(g>>1), half (g&1);
            // physical chunk = logical ^ q7 (row swizzle)
            *(uint2*)(prow + (((2 * cb + (g >> 1)) ^ q7) << 3) + ((g & 1) << 2)) = pw;
        }
        // own-row reads (same 4 lanes wrote this row); compiler inserts lgkm waits
        short8 ap0 = *(const short8*)(prow + ((g ^ q7) << 3));
        short8 ap1 = *(const short8*)(prow + (((4 + g) ^ q7) << 3));
        __builtin_amdgcn_s_setprio(1);
        sacc = MFMA(ap0, ones, sacc);              // exact row-sums of rounded P
        sacc = MFMA(ap1, ones, sacc);
#pragma unroll
        for (int cb = 0; cb < 4; cb++) {
            short8 bv0 = frag(Vs, cb * 16 + qr, g);
            short8 bv1 = frag(Vs, cb * 16 + qr, 4 + g);
            o[cb] = MFMA(ap0, bv0, o[cb]);
            o[cb] = MFMA(ap1, bv1, o[cb]);
        }
        __builtin_amdgcn_s_setprio(0);
        asm volatile("s_barrier" ::: "memory");    // reads of buf[kt&1] done
    }
    const int b = bh >> 4, h = bh & 15;
#pragma unroll
    for (int r = 0; r < 4; r++) {
        int lq = q0 + w * 16 + g * 4 + r;
        if (lq >= Lv) continue;
        float inv = 1.f / sacc[r];
        size_t ob = ((size_t)(b * 1025 + lq)) * 1024 + h * 64;
#pragma unroll
        for (int cb = 0; cb < 4; cb++)
            AO[ob + cb * 16 + qr] = f2b(o[cb][r] * inv);
    }
}

// ---------------- Proj GEMM + bias, fp32 out --------------------------------
// 1-D grid with bijective XCD swizzle (1032 = 8*129).
__global__ __launch_bounds__(256, 4) void gemm_proj(const ushort_t* __restrict__ A,
                                                    const ushort_t* __restrict__ W,
                                                    const float* __restrict__ bias,
                                                    float* __restrict__ out) {
    __shared__ uint4 sm[2112];                     // 33792 B
    ushort_t* As = (ushort_t*)sm;
    ushort_t* Bs = As + 128 * 64;
    const int t = threadIdx.x;
    const int w = t >> 6, l = t & 63;
    const int wg = blockIdx.x;
    const int nid = (wg & 7) * 129 + (wg >> 3);    // XCD swizzle, bijective
    const int m0 = (nid >> 3) * 128, n0 = (nid & 7) * 128;
    const int wm = (w >> 1) * 64, wn = (w & 1) * 64;
    const int srow = (w * 32) + (l >> 3);
    const int scs = (l & 7) ^ (srow & 7);
    f32x4 acc[4][4] = {};
    for (int k0 = 0; k0 < 1024; k0 += 64) {
        __syncthreads();
#pragma unroll
        for (int i = 0; i < 4; i++) {
            int row = srow + i * 8;
            gl2lds16(A + (size_t)(m0 + row) * 1024 + k0 + scs * 8,
                     As + (w * 32 + i * 8) * 64);
            gl2lds16(W + (size_t)(n0 + row) * 1024 + k0 + scs * 8,
                     Bs + (w * 32 + i * 8) * 64);
        }
        __syncthreads();
#pragma unroll
        for (int kb = 0; kb < 2; kb++) {
            short8 af[4], bf[4];
#pragma unroll
            for (int mb = 0; mb < 4; mb++)
                af[mb] = frag(As, wm + mb * 16 + (l & 15), kb * 4 + (l >> 4));
#pragma unroll
            for (int nb = 0; nb < 4; nb++)
                bf[nb] = frag(Bs, wn + nb * 16 + (l & 15), kb * 4 + (l >> 4));
#pragma unroll
            for (int mb = 0; mb < 4; mb++)
#pragma unroll
                for (int nb = 0; nb < 4; nb++)
                    acc[mb][nb] = MFMA(af[mb], bf[nb], acc[mb][nb]);
        }
    }
    // ---- epilogue: stage fp32 in 64-row halves, store 512-B rows ----
    float bias4[4];
#pragma unroll
    for (int nb = 0; nb < 4; nb++) bias4[nb] = bias[n0 + wn + nb * 16 + (l & 15)];
    float (*Sf)[132] = (float(*)[132])sm;          // 64x132 fp32 = 33792 B
#pragma unroll
    for (int half = 0; half < 2; half++) {
        __syncthreads();
        if ((w >> 1) == half) {
#pragma unroll
            for (int mb = 0; mb < 4; mb++)
#pragma unroll
                for (int r = 0; r < 4; r++)
#pragma unroll
                    for (int nb = 0; nb < 4; nb++)
                        Sf[mb * 16 + (l >> 4) * 4 + r][wn + nb * 16 + (l & 15)] =
                            acc[mb][nb][r] + bias4[nb];
        }
        __syncthreads();
#pragma unroll
        for (int it = 0; it < 8; it++) {
            int rr = it * 8 + w * 2 + (l >> 5);
            int m = m0 + half * 64 + rr;
            if (m < Mv)
                *(float4*)(out + (size_t)m * 1024 + n0 + (l & 31) * 4) =
                    *(const float4*)&Sf[rr][(l & 31) * 4];
        }
    }
}

extern "C" void kernel_launch(void* const* d_in, const int* in_sizes, int n_in,
                              void* d_out, int out_size, void* d_ws, size_t ws_size,
                              hipStream_t stream) {
    (void)in_sizes; (void)n_in; (void)out_size; (void)ws_size;
    const float* x      = (const float*)d_in[0];
    const float* sinp   = (const float*)d_in[1];
    const float* cosp   = (const float*)d_in[2];
    const float* qkv_w  = (const float*)d_in[3];
    const float* proj_w = (const float*)d_in[4];
    const float* proj_b = (const float*)d_in[5];
    float* out = (float*)d_out;

    const size_t SZQ = (size_t)BHv * LpQ * 64;     // Q tensor (bf16 elems)
    const size_t SZH = (size_t)BHv * LpD * 64;     // per K/V tensor (bf16 elems)
    ushort_t* xb  = (ushort_t*)d_ws;               // [Mp][1024]
    ushort_t* qwb = xb + (size_t)Mp * 1024;        // [3072][1024]
    ushort_t* pwb = qwb + (size_t)3072 * 1024;     // [1024][1024]
    ushort_t* Qb  = pwb + (size_t)1024 * 1024;     // [BH][LpQ][64]
    ushort_t* Kb  = Qb + SZQ;                      // [BH][LpD][64]
    ushort_t* Vb  = Kb + SZH;
    ushort_t* Vt  = Vb + SZH;                      // [BH][64][LpD]
    ushort_t* AO  = xb;                            // alias: xb dead after gemm_qkv;
                                                   // in-order stream, conv rewrites xb

    dim3 blk(256);
    conv_bf16<<<dim3(Mp * 1024 / 1024), blk, 0, stream>>>(x, xb, Mv * 1024, Mp * 1024);
    conv_bf16<<<dim3(3072 * 1024 / 1024), blk, 0, stream>>>(qkv_w, qwb, 3072 * 1024, 3072 * 1024);
    conv_bf16<<<dim3(1024 * 1024 / 1024), blk, 0, stream>>>(proj_w, pwb, 1024 * 1024, 1024 * 1024);
    zero_qpad<<<dim3(1016), blk, 0, stream>>>(Qb);
    gemm_qkv<<<dim3(3096), blk, 0, stream>>>(xb, qwb, Qb, Kb, Vb, sinp, cosp);
    transpose_v<<<dim3(17, BHv), blk, 0, stream>>>(Vb, Vt);
    attn_mfma<<<dim3(9 * BHv), dim3(512), 0, stream>>>(Qb, Kb, Vt, AO);
    gemm_proj<<<dim3(1032), blk, 0, stream>>>(AO, pwb, proj_b, out);
}